// Round 6
// baseline (503.711 us; speedup 1.0000x reference)
//
#include <hip/hip_runtime.h>

typedef unsigned int u32;
typedef unsigned short u16;
typedef __attribute__((ext_vector_type(8))) short bf16x8;
typedef __attribute__((ext_vector_type(4))) float f32x4;

__device__ __forceinline__ float bf2f(u16 u){ return __uint_as_float(((u32)u) << 16); }
__device__ __forceinline__ u16 f2bf(float f){
  u32 x = __float_as_uint(f);
  return (u16)((x + 0x7fffu + ((x >> 16) & 1u)) >> 16);  // RNE
}

// ---------- prep: WcatT[640][128] ([q|skip|k|v|gcn], [outcol][k]) + bcat, w1T, w2T (bf16) ----------
__global__ void k_prep_all(const float* wq, const float* bq, const float* wsk, const float* bsk,
                           const float* wk, const float* bk, const float* wv, const float* bv,
                           const float* wg, const float* w1, const float* w2,
                           u16* WcatT, float* bcat, u16* w1T, u16* w2T){
  int idx = blockIdx.x * 256 + threadIdx.x;
  if (idx < 640 * 128){
    int col = idx >> 7, k = idx & 127;
    int blk = col >> 7, c = col & 127;
    const float* w = (blk==0)?wq:(blk==1)?wsk:(blk==2)?wk:(blk==3)?wv:wg;
    WcatT[idx] = f2bf(w[k * 128 + c]);
    if (k == 0){
      const float* b = (blk==0)?bq:(blk==1)?bsk:(blk==2)?bk:(blk==3)?bv:nullptr;
      bcat[col] = b ? b[c] : 0.0f;   // gcn bias added after aggregation
    }
  } else if (idx < 640*128 + 256*128){
    int j = idx - 640*128; int c = j >> 7, k = j & 127;
    w1T[j] = f2bf(w1[k * 256 + c]);
  } else if (idx < 640*128 + 256*128 + 128*256){
    int j = idx - (640*128 + 256*128); int c = j >> 8, k = j & 255;
    w2T[j] = f2bf(w2[k * 128 + c]);
  }
}

// ---------- x (f32) -> xB (bf16) ----------
__global__ void k_cvt(const float* __restrict__ x, u16* __restrict__ xB, int n){
  int i = (blockIdx.x * 256 + threadIdx.x) * 4;
  if (i >= n) return;
  float4 v = *(const float4*)(x + i);
  ushort4 o; o.x = f2bf(v.x); o.y = f2bf(v.y); o.z = f2bf(v.z); o.w = f2bf(v.w);
  *(ushort4*)(xB + i) = o;
}

// ---------- graph prep (edge_index int32: src=ei[e], dst=ei[E+e]) ----------
__global__ void k_hist(const int* __restrict__ ei, int E, int* __restrict__ deg){
  int e = blockIdx.x * 256 + threadIdx.x;
  if (e >= E) return;
  atomicAdd(&deg[ei[E + e]], 1);
}
__global__ void k_scan_a(const int* __restrict__ deg, int N, int* __restrict__ bsum){
  __shared__ int sh[256];
  int b = blockIdx.x, t = threadIdx.x;
  int base = b * 1024 + t * 4, s = 0;
  #pragma unroll
  for (int j = 0; j < 4; j++){ int i = base + j; if (i < N) s += deg[i]; }
  sh[t] = s; __syncthreads();
  for (int off = 128; off > 0; off >>= 1){ if (t < off) sh[t] += sh[t + off]; __syncthreads(); }
  if (t == 0) bsum[b] = sh[0];
}
__global__ void k_scan_b(const int* __restrict__ bsum, int NB, int* __restrict__ boff){
  __shared__ int sh[1024];
  int t = threadIdx.x;
  int self = (t < NB) ? bsum[t] : 0;
  sh[t] = self; __syncthreads();
  for (int off = 1; off < 1024; off <<= 1){
    int v = sh[t]; int add = (t >= off) ? sh[t - off] : 0;
    __syncthreads(); sh[t] = v + add; __syncthreads();
  }
  if (t < NB) boff[t] = sh[t] - self;
}
__global__ void k_scan_c(const int* __restrict__ deg, int N, int E,
                         const int* __restrict__ boff, int* __restrict__ rowptr){
  __shared__ int sh[256];
  int b = blockIdx.x, t = threadIdx.x;
  int base = b * 1024 + t * 4;
  int d[4]; int ts = 0;
  #pragma unroll
  for (int j = 0; j < 4; j++){ int i = base + j; d[j] = (i < N) ? deg[i] : 0; ts += d[j]; }
  sh[t] = ts; __syncthreads();
  for (int off = 1; off < 256; off <<= 1){
    int v = sh[t]; int add = (t >= off) ? sh[t - off] : 0;
    __syncthreads(); sh[t] = v + add; __syncthreads();
  }
  int excl = sh[t] - ts + boff[b];
  #pragma unroll
  for (int j = 0; j < 4; j++){ int i = base + j; if (i < N) rowptr[i] = excl; excl += d[j]; }
  if (b == 0 && t == 0) rowptr[N] = E;
}
__global__ void k_dinv(const int* __restrict__ deg, int N, float* __restrict__ dinv){
  int i = blockIdx.x * 256 + threadIdx.x;
  if (i < N) dinv[i] = deg[i] > 0 ? rsqrtf((float)deg[i]) : 0.0f;
}
__global__ void k_csr(const int* __restrict__ ei, int E,
                      const int* __restrict__ rowptr, int* __restrict__ fill, int* __restrict__ csr){
  int e = blockIdx.x * 256 + threadIdx.x;
  if (e >= E) return;
  int d = ei[E + e];
  int pos = rowptr[d] + atomicAdd(&fill[d], 1);
  csr[pos] = ei[e];
}

// ---------- MFMA tile helpers: 128 rows x 128 halves, XOR-swizzled LDS ----------
__device__ __forceinline__ void stageTile(const u16* __restrict__ g, int ldg, int row0, int rclamp,
                                          int kofs, u16* lds){
  int t = threadIdx.x;
  #pragma unroll
  for (int p = 0; p < 8; p++){
    int chunk = p * 256 + t;
    int r = chunk >> 4;
    int cs = (chunk & 15) << 3;
    int rg = row0 + r; if (rg >= rclamp) rg = rclamp - 1;
    bf16x8 v = *(const bf16x8*)(g + (size_t)rg * ldg + kofs + cs);
    *(bf16x8*)(lds + r * 128 + (cs ^ ((r & 7) << 3))) = v;
  }
}
__device__ __forceinline__ bf16x8 ldFrag(const u16* lds, int r, int k0){
  return *(const bf16x8*)(lds + r * 128 + (k0 ^ ((r & 7) << 3)));
}

// ---------- GEMM1 (MFMA): [q | xr | k,v,h] bf16 = xB @ WcatT^T + bcat ----------
__global__ __launch_bounds__(256) void k_gemm1(const u16* __restrict__ xB, const u16* __restrict__ WcatT,
    const float* __restrict__ bcat, u16* __restrict__ qB, u16* __restrict__ xrB,
    u16* __restrict__ kvhB, int N){
  __shared__ u16 As[128 * 128];
  __shared__ u16 Bs[128 * 128];
  int row0 = blockIdx.x * 128, cb = blockIdx.y;
  stageTile(xB, 128, row0, N, 0, As);
  stageTile(WcatT, 128, cb * 128, 1 << 30, 0, Bs);
  __syncthreads();
  int t = threadIdx.x, l = t & 63, w = t >> 6;
  int wm = w >> 1, wn = w & 1;
  int c16 = l & 15, g = l >> 4;
  f32x4 acc[4][4];
  #pragma unroll
  for (int mi = 0; mi < 4; mi++)
    #pragma unroll
    for (int ni = 0; ni < 4; ni++) acc[mi][ni] = (f32x4){0.f, 0.f, 0.f, 0.f};
  #pragma unroll
  for (int kk = 0; kk < 4; kk++){
    int k0 = kk * 32 + g * 8;
    bf16x8 af[4], bfr[4];
    #pragma unroll
    for (int mi = 0; mi < 4; mi++) af[mi] = ldFrag(As, wm * 64 + mi * 16 + c16, k0);
    #pragma unroll
    for (int ni = 0; ni < 4; ni++) bfr[ni] = ldFrag(Bs, wn * 64 + ni * 16 + c16, k0);
    #pragma unroll
    for (int mi = 0; mi < 4; mi++)
      #pragma unroll
      for (int ni = 0; ni < 4; ni++)
        acc[mi][ni] = __builtin_amdgcn_mfma_f32_16x16x32_bf16(af[mi], bfr[ni], acc[mi][ni], 0, 0, 0);
  }
  u16* dst; int ld, cofs;
  if (cb == 0){ dst = qB;  ld = 128; cofs = 0; }
  else if (cb == 1){ dst = xrB; ld = 128; cofs = 0; }
  else { dst = kvhB; ld = 384; cofs = (cb - 2) * 128; }
  float bias[4];
  #pragma unroll
  for (int ni = 0; ni < 4; ni++) bias[ni] = bcat[cb * 128 + wn * 64 + ni * 16 + c16];
  #pragma unroll
  for (int mi = 0; mi < 4; mi++){
    #pragma unroll
    for (int r = 0; r < 4; r++){
      int row = row0 + wm * 64 + mi * 16 + g * 4 + r;
      if (row < N){
        #pragma unroll
        for (int ni = 0; ni < 4; ni++)
          dst[(size_t)row * ld + cofs + wn * 64 + ni * 16 + c16] = f2bf(acc[mi][ni][r] + bias[ni]);
      }
    }
  }
}

// ---------- edge pass: per-dst attention + GCN aggregate + beta gate + LN1, one wave per node ----
// 2x edge unroll: both edges' 6 gather loads issued together (2x MLP), reduce chains interleaved.
__global__ __launch_bounds__(256) void k_edge(const u16* __restrict__ qB, const u16* __restrict__ xrB,
    const u16* __restrict__ kvhB,
    const int* __restrict__ csr, const int* __restrict__ rowptr, const float* __restrict__ dinv,
    const float* __restrict__ bgcn, const float* __restrict__ wbeta,
    const float* __restrict__ lng, const float* __restrict__ lnb,
    const float* __restrict__ lwp, const float* __restrict__ gwp,
    float* __restrict__ xn, u16* __restrict__ xnB, int N){
  int lane = threadIdx.x & 63;
  int n = blockIdx.x * 4 + (threadIdx.x >> 6);
  if (n >= N) return;
  int ro = rowptr[n], re = rowptr[n + 1];
  u32 qu = *(const u32*)(qB + (size_t)n * 128 + 2 * lane);
  float q0 = bf2f((u16)(qu & 0xffff)), q1 = bf2f((u16)(qu >> 16));
  float av0 = 0, av1 = 0, ah0 = 0, ah1 = 0, den = 0;
  const float SC = 0.17677669529663687f;  // 1/sqrt(32)
  int e = ro;
  for (; e + 1 < re; e += 2){
    int s0 = csr[e], s1 = csr[e + 1];
    const u16* f0 = kvhB + (size_t)s0 * 384;
    const u16* f1 = kvhB + (size_t)s1 * 384;
    u32 ku0 = *(const u32*)(f0 + 2 * lane);
    u32 ku1 = *(const u32*)(f1 + 2 * lane);
    u32 vu0 = *(const u32*)(f0 + 128 + 2 * lane);
    u32 vu1 = *(const u32*)(f1 + 128 + 2 * lane);
    u32 hu0 = *(const u32*)(f0 + 256 + 2 * lane);
    u32 hu1 = *(const u32*)(f1 + 256 + 2 * lane);
    float dv0 = dinv[s0], dv1 = dinv[s1];
    float pa0 = q0 * bf2f((u16)(ku0 & 0xffff)) + q1 * bf2f((u16)(ku0 >> 16));
    float pa1 = q0 * bf2f((u16)(ku1 & 0xffff)) + q1 * bf2f((u16)(ku1 >> 16));
    pa0 += __shfl_xor(pa0, 1); pa1 += __shfl_xor(pa1, 1);
    pa0 += __shfl_xor(pa0, 2); pa1 += __shfl_xor(pa1, 2);
    pa0 += __shfl_xor(pa0, 4); pa1 += __shfl_xor(pa1, 4);
    pa0 += __shfl_xor(pa0, 8); pa1 += __shfl_xor(pa1, 8);
    float p0 = __expf(pa0 * SC);
    float p1 = __expf(pa1 * SC);
    av0 += p0 * bf2f((u16)(vu0 & 0xffff)) + p1 * bf2f((u16)(vu1 & 0xffff));
    av1 += p0 * bf2f((u16)(vu0 >> 16))    + p1 * bf2f((u16)(vu1 >> 16));
    ah0 += dv0 * bf2f((u16)(hu0 & 0xffff)) + dv1 * bf2f((u16)(hu1 & 0xffff));
    ah1 += dv0 * bf2f((u16)(hu0 >> 16))    + dv1 * bf2f((u16)(hu1 >> 16));
    den += p0 + p1;
  }
  if (e < re){
    int s = csr[e];
    const u16* fb = kvhB + (size_t)s * 384;
    u32 ku = *(const u32*)(fb + 2 * lane);
    u32 vu = *(const u32*)(fb + 128 + 2 * lane);
    u32 hu = *(const u32*)(fb + 256 + 2 * lane);
    float dv = dinv[s];
    float part = q0 * bf2f((u16)(ku & 0xffff)) + q1 * bf2f((u16)(ku >> 16));
    part += __shfl_xor(part, 1);
    part += __shfl_xor(part, 2);
    part += __shfl_xor(part, 4);
    part += __shfl_xor(part, 8);
    float p = __expf(part * SC);
    av0 += p * bf2f((u16)(vu & 0xffff));
    av1 += p * bf2f((u16)(vu >> 16));
    ah0 += dv * bf2f((u16)(hu & 0xffff));
    ah1 += dv * bf2f((u16)(hu >> 16));
    den += p;
  }
  float at0 = den > 0 ? av0 / den : 0.0f;
  float at1 = den > 0 ? av1 / den : 0.0f;
  u32 xru = *(const u32*)(xrB + (size_t)n * 128 + 2 * lane);
  float xr0 = bf2f((u16)(xru & 0xffff)), xr1 = bf2f((u16)(xru >> 16));
  float z = at0 * wbeta[2*lane] + at1 * wbeta[2*lane+1]
          + xr0 * wbeta[128 + 2*lane] + xr1 * wbeta[129 + 2*lane]
          + (at0 - xr0) * wbeta[256 + 2*lane] + (at1 - xr1) * wbeta[257 + 2*lane];
  z += __shfl_xor(z, 1); z += __shfl_xor(z, 2); z += __shfl_xor(z, 4);
  z += __shfl_xor(z, 8); z += __shfl_xor(z, 16); z += __shfl_xor(z, 32);
  float beta = 1.0f / (1.0f + __expf(-z));
  float dn = dinv[n];
  float l0 = dn * ah0 + bgcn[2*lane], l1 = dn * ah1 + bgcn[2*lane+1];
  float g0 = beta * xr0 + (1.0f - beta) * at0;
  float g1v = beta * xr1 + (1.0f - beta) * at1;
  float lw = lwp[0], gw = gwp[0];
  float t0 = 2.0f * (lw * l0 + gw * g0);
  float t1 = 2.0f * (lw * l1 + gw * g1v);
  float s = t0 + t1, sq = t0 * t0 + t1 * t1;
  s += __shfl_xor(s, 1);  sq += __shfl_xor(sq, 1);
  s += __shfl_xor(s, 2);  sq += __shfl_xor(sq, 2);
  s += __shfl_xor(s, 4);  sq += __shfl_xor(sq, 4);
  s += __shfl_xor(s, 8);  sq += __shfl_xor(sq, 8);
  s += __shfl_xor(s, 16); sq += __shfl_xor(sq, 16);
  s += __shfl_xor(s, 32); sq += __shfl_xor(sq, 32);
  float mu = s * (1.0f / 128.0f);
  float var = sq * (1.0f / 128.0f) - mu * mu;
  float inv = rsqrtf(var + 1e-5f);
  float o0 = (t0 - mu) * inv * lng[2*lane] + lnb[2*lane];
  float o1 = (t1 - mu) * inv * lng[2*lane+1] + lnb[2*lane+1];
  *(float2*)(xn + (size_t)n * 128 + 2 * lane) = make_float2(o0, o1);
  u32 pk = (u32)f2bf(o0) | ((u32)f2bf(o1) << 16);
  *(u32*)(xnB + (size_t)n * 128 + 2 * lane) = pk;
}

// ---------- FFN1 (MFMA): hid(bf16) = relu(xnB @ w1 + b1) ----------
__global__ __launch_bounds__(256) void k_ffn1(const u16* __restrict__ xnB, const u16* __restrict__ w1T,
    const float* __restrict__ b1, u16* __restrict__ hid, int N){
  __shared__ u16 As[128 * 128];
  __shared__ u16 Bs[128 * 128];
  int row0 = blockIdx.x * 128, cb = blockIdx.y;
  stageTile(xnB, 128, row0, N, 0, As);
  stageTile(w1T, 128, cb * 128, 1 << 30, 0, Bs);
  __syncthreads();
  int t = threadIdx.x, l = t & 63, w = t >> 6;
  int wm = w >> 1, wn = w & 1;
  int c16 = l & 15, g = l >> 4;
  f32x4 acc[4][4];
  #pragma unroll
  for (int mi = 0; mi < 4; mi++)
    #pragma unroll
    for (int ni = 0; ni < 4; ni++) acc[mi][ni] = (f32x4){0.f, 0.f, 0.f, 0.f};
  #pragma unroll
  for (int kk = 0; kk < 4; kk++){
    int k0 = kk * 32 + g * 8;
    bf16x8 af[4], bfr[4];
    #pragma unroll
    for (int mi = 0; mi < 4; mi++) af[mi] = ldFrag(As, wm * 64 + mi * 16 + c16, k0);
    #pragma unroll
    for (int ni = 0; ni < 4; ni++) bfr[ni] = ldFrag(Bs, wn * 64 + ni * 16 + c16, k0);
    #pragma unroll
    for (int mi = 0; mi < 4; mi++)
      #pragma unroll
      for (int ni = 0; ni < 4; ni++)
        acc[mi][ni] = __builtin_amdgcn_mfma_f32_16x16x32_bf16(af[mi], bfr[ni], acc[mi][ni], 0, 0, 0);
  }
  float bias[4];
  #pragma unroll
  for (int ni = 0; ni < 4; ni++) bias[ni] = b1[cb * 128 + wn * 64 + ni * 16 + c16];
  #pragma unroll
  for (int mi = 0; mi < 4; mi++){
    #pragma unroll
    for (int r = 0; r < 4; r++){
      int row = row0 + wm * 64 + mi * 16 + g * 4 + r;
      if (row < N){
        #pragma unroll
        for (int ni = 0; ni < 4; ni++)
          hid[(size_t)row * 256 + cb * 128 + wn * 64 + ni * 16 + c16] =
              f2bf(fmaxf(acc[mi][ni][r] + bias[ni], 0.0f));
      }
    }
  }
}

// ---------- FFN2 (MFMA) + residual + LN2 -> out (f32, in place over xn) ----------
__global__ __launch_bounds__(256) void k_ffn2(const u16* __restrict__ hid, const u16* __restrict__ w2T,
    const float* __restrict__ b2, const float* __restrict__ xnf,
    const float* __restrict__ g2, const float* __restrict__ bt2,
    float* __restrict__ out, int N){
  __shared__ u16 As[128 * 128];
  __shared__ u16 Bs[128 * 128];
  int row0 = blockIdx.x * 128;
  int t = threadIdx.x, l = t & 63, w = t >> 6;
  int c16 = l & 15, g = l >> 4;
  f32x4 acc[2][8];
  #pragma unroll
  for (int mi = 0; mi < 2; mi++)
    #pragma unroll
    for (int ni = 0; ni < 8; ni++) acc[mi][ni] = (f32x4){0.f, 0.f, 0.f, 0.f};
  for (int kc = 0; kc < 2; kc++){
    if (kc) __syncthreads();
    stageTile(hid, 256, row0, N, kc * 128, As);
    stageTile(w2T, 256, 0, 1 << 30, kc * 128, Bs);
    __syncthreads();
    #pragma unroll
    for (int kk = 0; kk < 4; kk++){
      int k0 = kk * 32 + g * 8;
      bf16x8 af[2], bfr[8];
      #pragma unroll
      for (int mi = 0; mi < 2; mi++) af[mi] = ldFrag(As, w * 32 + mi * 16 + c16, k0);
      #pragma unroll
      for (int ni = 0; ni < 8; ni++) bfr[ni] = ldFrag(Bs, ni * 16 + c16, k0);
      #pragma unroll
      for (int mi = 0; mi < 2; mi++)
        #pragma unroll
        for (int ni = 0; ni < 8; ni++)
          acc[mi][ni] = __builtin_amdgcn_mfma_f32_16x16x32_bf16(af[mi], bfr[ni], acc[mi][ni], 0, 0, 0);
    }
  }
  float b2c[8], g2c[8], btc[8];
  #pragma unroll
  for (int ni = 0; ni < 8; ni++){
    int col = ni * 16 + c16;
    b2c[ni] = b2[col]; g2c[ni] = g2[col]; btc[ni] = bt2[col];
  }
  #pragma unroll
  for (int mi = 0; mi < 2; mi++){
    #pragma unroll
    for (int r = 0; r < 4; r++){
      int row = row0 + w * 32 + mi * 16 + g * 4 + r;
      int rc = row < N ? row : N - 1;
      float z[8]; float s = 0.f, sq = 0.f;
      #pragma unroll
      for (int ni = 0; ni < 8; ni++){
        z[ni] = acc[mi][ni][r] + b2c[ni] + xnf[(size_t)rc * 128 + ni * 16 + c16];
        s += z[ni]; sq += z[ni] * z[ni];
      }
      s += __shfl_xor(s, 1); sq += __shfl_xor(sq, 1);
      s += __shfl_xor(s, 2); sq += __shfl_xor(sq, 2);
      s += __shfl_xor(s, 4); sq += __shfl_xor(sq, 4);
      s += __shfl_xor(s, 8); sq += __shfl_xor(sq, 8);
      float mu = s * (1.0f / 128.0f);
      float var = sq * (1.0f / 128.0f) - mu * mu;
      float inv = rsqrtf(var + 1e-5f);
      if (row < N){
        #pragma unroll
        for (int ni = 0; ni < 8; ni++)
          out[(size_t)row * 128 + ni * 16 + c16] = (z[ni] - mu) * inv * g2c[ni] + btc[ni];
      }
    }
  }
}

extern "C" void kernel_launch(void* const* d_in, const int* in_sizes, int n_in,
                              void* d_out, int out_size, void* d_ws, size_t ws_size,
                              hipStream_t stream){
  const float* x      = (const float*)d_in[0];
  const int*   ei     = (const int*)d_in[1];
  const float* w_gcn  = (const float*)d_in[2];
  const float* b_gcn  = (const float*)d_in[3];
  const float* w_q    = (const float*)d_in[4];
  const float* b_q    = (const float*)d_in[5];
  const float* w_k    = (const float*)d_in[6];
  const float* b_k    = (const float*)d_in[7];
  const float* w_v    = (const float*)d_in[8];
  const float* b_v    = (const float*)d_in[9];
  const float* w_skip = (const float*)d_in[10];
  const float* b_skip = (const float*)d_in[11];
  const float* w_beta = (const float*)d_in[12];
  const float* ln1_g  = (const float*)d_in[13];
  const float* ln1_b  = (const float*)d_in[14];
  const float* ln2_g  = (const float*)d_in[15];
  const float* ln2_b  = (const float*)d_in[16];
  const float* w1     = (const float*)d_in[17];
  const float* b1     = (const float*)d_in[18];
  const float* w2     = (const float*)d_in[19];
  const float* b2     = (const float*)d_in[20];
  const float* lw     = (const float*)d_in[21];
  const float* gw     = (const float*)d_in[22];
  int N = in_sizes[0] / 128;
  int E = in_sizes[1] / 2;
  float* outf = (float*)d_out;
  float* xn   = (float*)d_out;   // xn lives in d_out; ffn2 reads-then-overwrites per row

  char* ws = (char*)d_ws;
  size_t off = 0;
  auto alloc = [&](size_t bytes) -> char* {
    char* p = ws + off; off += (bytes + 255) & ~(size_t)255; return p;
  };
  u16* kvhB   = (u16*)alloc((size_t)N * 384 * 2);   // [k | v | h] bf16; aliased by hid after edge
  u16* xrB    = (u16*)alloc((size_t)N * 128 * 2);
  u16* qB     = (u16*)alloc((size_t)N * 128 * 2);
  u16* xB     = (u16*)alloc((size_t)N * 128 * 2);   // aliased by xnB after gemm1
  int* csr    = (int*)alloc((size_t)E * 4);
  int* deg    = (int*)alloc((size_t)N * 4);
  int* rowptr = (int*)alloc((size_t)(N + 1) * 4);
  int* fill   = (int*)alloc((size_t)N * 4);
  float* dinv = (float*)alloc((size_t)N * 4);
  int NB = (N + 1023) >> 10;
  int* bsum   = (int*)alloc((size_t)NB * 4);
  int* boff   = (int*)alloc((size_t)NB * 4);
  u16* WcatT  = (u16*)alloc((size_t)640 * 128 * 2);
  float* bcat = (float*)alloc((size_t)640 * 4);
  u16* w1T    = (u16*)alloc((size_t)256 * 128 * 2);
  u16* w2T    = (u16*)alloc((size_t)128 * 256 * 2);
  u16* hid    = kvhB;            // alias: kvhB dead after k_edge (N*256*2 <= N*384*2)
  u16* xnB    = xB;              // alias: xB dead after k_gemm1

  if (off > ws_size) return;     // bail cleanly if workspace too small

  hipMemsetAsync(deg, 0, (size_t)N * 4, stream);
  hipMemsetAsync(fill, 0, (size_t)N * 4, stream);

  k_prep_all<<<576, 256, 0, stream>>>(w_q, b_q, w_skip, b_skip, w_k, b_k, w_v, b_v, w_gcn,
                                      w1, w2, WcatT, bcat, w1T, w2T);
  k_cvt<<<(N * 128 / 4 + 255) / 256, 256, 0, stream>>>(x, xB, N * 128);
  k_hist<<<(E + 255) / 256, 256, 0, stream>>>(ei, E, deg);
  k_scan_a<<<NB, 256, 0, stream>>>(deg, N, bsum);
  k_scan_b<<<1, 1024, 0, stream>>>(bsum, NB, boff);
  k_scan_c<<<NB, 256, 0, stream>>>(deg, N, E, boff, rowptr);
  k_dinv<<<(N + 255) / 256, 256, 0, stream>>>(deg, N, dinv);
  k_csr<<<(E + 255) / 256, 256, 0, stream>>>(ei, E, rowptr, fill, csr);

  int MB = (N + 127) / 128;
  dim3 g1(MB, 5);
  k_gemm1<<<g1, 256, 0, stream>>>(xB, WcatT, bcat, qB, xrB, kvhB, N);
  k_edge<<<(N + 3) / 4, 256, 0, stream>>>(qB, xrB, kvhB, csr, rowptr, dinv, b_gcn, w_beta,
                                          ln1_g, ln1_b, lw, gw, xn, xnB, N);
  dim3 f1(MB, 2);
  k_ffn1<<<f1, 256, 0, stream>>>(xnB, w1T, b1, hid, N);
  k_ffn2<<<MB, 256, 0, stream>>>(hid, w2T, b2, xn, ln2_g, ln2_b, outf, N);
}

// Round 7
// 472.705 us; speedup vs baseline: 1.0656x; 1.0656x over previous
//
#include <hip/hip_runtime.h>

typedef unsigned int u32;
typedef unsigned short u16;
typedef __attribute__((ext_vector_type(8))) short bf16x8;
typedef __attribute__((ext_vector_type(4))) float f32x4;

__device__ __forceinline__ float bf2f(u16 u){ return __uint_as_float(((u32)u) << 16); }
__device__ __forceinline__ float bf2f_lo(u32 u){ return __uint_as_float(u << 16); }
__device__ __forceinline__ float bf2f_hi(u32 u){ return __uint_as_float(u & 0xffff0000u); }
__device__ __forceinline__ u16 f2bf(float f){
  u32 x = __float_as_uint(f);
  return (u16)((x + 0x7fffu + ((x >> 16) & 1u)) >> 16);  // RNE
}

// ---------- prep: WcatT[640][128] ([q|skip|k|v|gcn], [outcol][k]) + bcat, w1T, w2T (bf16) ----------
__global__ void k_prep_all(const float* wq, const float* bq, const float* wsk, const float* bsk,
                           const float* wk, const float* bk, const float* wv, const float* bv,
                           const float* wg, const float* w1, const float* w2,
                           u16* WcatT, float* bcat, u16* w1T, u16* w2T){
  int idx = blockIdx.x * 256 + threadIdx.x;
  if (idx < 640 * 128){
    int col = idx >> 7, k = idx & 127;
    int blk = col >> 7, c = col & 127;
    const float* w = (blk==0)?wq:(blk==1)?wsk:(blk==2)?wk:(blk==3)?wv:wg;
    WcatT[idx] = f2bf(w[k * 128 + c]);
    if (k == 0){
      const float* b = (blk==0)?bq:(blk==1)?bsk:(blk==2)?bk:(blk==3)?bv:nullptr;
      bcat[col] = b ? b[c] : 0.0f;   // gcn bias added after aggregation
    }
  } else if (idx < 640*128 + 256*128){
    int j = idx - 640*128; int c = j >> 7, k = j & 127;
    w1T[j] = f2bf(w1[k * 256 + c]);
  } else if (idx < 640*128 + 256*128 + 128*256){
    int j = idx - (640*128 + 256*128); int c = j >> 8, k = j & 255;
    w2T[j] = f2bf(w2[k * 128 + c]);
  }
}

// ---------- x (f32) -> xB (bf16) ----------
__global__ void k_cvt(const float* __restrict__ x, u16* __restrict__ xB, int n){
  int i = (blockIdx.x * 256 + threadIdx.x) * 4;
  if (i >= n) return;
  float4 v = *(const float4*)(x + i);
  ushort4 o; o.x = f2bf(v.x); o.y = f2bf(v.y); o.z = f2bf(v.z); o.w = f2bf(v.w);
  *(ushort4*)(xB + i) = o;
}

// ---------- graph prep (edge_index int32: src=ei[e], dst=ei[E+e]) ----------
__global__ void k_hist(const int* __restrict__ ei, int E, int* __restrict__ deg){
  int e = blockIdx.x * 256 + threadIdx.x;
  if (e >= E) return;
  atomicAdd(&deg[ei[E + e]], 1);
}
__global__ void k_scan_a(const int* __restrict__ deg, int N, int* __restrict__ bsum){
  __shared__ int sh[256];
  int b = blockIdx.x, t = threadIdx.x;
  int base = b * 1024 + t * 4, s = 0;
  #pragma unroll
  for (int j = 0; j < 4; j++){ int i = base + j; if (i < N) s += deg[i]; }
  sh[t] = s; __syncthreads();
  for (int off = 128; off > 0; off >>= 1){ if (t < off) sh[t] += sh[t + off]; __syncthreads(); }
  if (t == 0) bsum[b] = sh[0];
}
__global__ void k_scan_b(const int* __restrict__ bsum, int NB, int* __restrict__ boff){
  __shared__ int sh[1024];
  int t = threadIdx.x;
  int self = (t < NB) ? bsum[t] : 0;
  sh[t] = self; __syncthreads();
  for (int off = 1; off < 1024; off <<= 1){
    int v = sh[t]; int add = (t >= off) ? sh[t - off] : 0;
    __syncthreads(); sh[t] = v + add; __syncthreads();
  }
  if (t < NB) boff[t] = sh[t] - self;
}
__global__ void k_scan_c(const int* __restrict__ deg, int N, int E,
                         const int* __restrict__ boff, int* __restrict__ rowptr){
  __shared__ int sh[256];
  int b = blockIdx.x, t = threadIdx.x;
  int base = b * 1024 + t * 4;
  int d[4]; int ts = 0;
  #pragma unroll
  for (int j = 0; j < 4; j++){ int i = base + j; d[j] = (i < N) ? deg[i] : 0; ts += d[j]; }
  sh[t] = ts; __syncthreads();
  for (int off = 1; off < 256; off <<= 1){
    int v = sh[t]; int add = (t >= off) ? sh[t - off] : 0;
    __syncthreads(); sh[t] = v + add; __syncthreads();
  }
  int excl = sh[t] - ts + boff[b];
  #pragma unroll
  for (int j = 0; j < 4; j++){ int i = base + j; if (i < N) rowptr[i] = excl; excl += d[j]; }
  if (b == 0 && t == 0) rowptr[N] = E;
}
__global__ void k_dinv(const int* __restrict__ deg, int N, float* __restrict__ dinv){
  int i = blockIdx.x * 256 + threadIdx.x;
  if (i < N) dinv[i] = deg[i] > 0 ? rsqrtf((float)deg[i]) : 0.0f;
}
__global__ void k_csr(const int* __restrict__ ei, int E,
                      const int* __restrict__ rowptr, int* __restrict__ fill, int* __restrict__ csr){
  int e = blockIdx.x * 256 + threadIdx.x;
  if (e >= E) return;
  int d = ei[E + e];
  int pos = rowptr[d] + atomicAdd(&fill[d], 1);
  csr[pos] = ei[e];
}

// ---------- MFMA tile helpers: 128 rows x 128 halves, XOR-swizzled LDS ----------
__device__ __forceinline__ void stageTile(const u16* __restrict__ g, int ldg, int row0, int rclamp,
                                          int kofs, u16* lds){
  int t = threadIdx.x;
  #pragma unroll
  for (int p = 0; p < 8; p++){
    int chunk = p * 256 + t;
    int r = chunk >> 4;
    int cs = (chunk & 15) << 3;
    int rg = row0 + r; if (rg >= rclamp) rg = rclamp - 1;
    bf16x8 v = *(const bf16x8*)(g + (size_t)rg * ldg + kofs + cs);
    *(bf16x8*)(lds + r * 128 + (cs ^ ((r & 7) << 3))) = v;
  }
}
__device__ __forceinline__ bf16x8 ldFrag(const u16* lds, int r, int k0){
  return *(const bf16x8*)(lds + r * 128 + (k0 ^ ((r & 7) << 3)));
}

// ---------- GEMM1 (MFMA): [q | xr | k,v,h] bf16 = xB @ WcatT^T + bcat ----------
__global__ __launch_bounds__(256) void k_gemm1(const u16* __restrict__ xB, const u16* __restrict__ WcatT,
    const float* __restrict__ bcat, u16* __restrict__ qB, u16* __restrict__ xrB,
    u16* __restrict__ kvhB, int N){
  __shared__ u16 As[128 * 128];
  __shared__ u16 Bs[128 * 128];
  int row0 = blockIdx.x * 128, cb = blockIdx.y;
  stageTile(xB, 128, row0, N, 0, As);
  stageTile(WcatT, 128, cb * 128, 1 << 30, 0, Bs);
  __syncthreads();
  int t = threadIdx.x, l = t & 63, w = t >> 6;
  int wm = w >> 1, wn = w & 1;
  int c16 = l & 15, g = l >> 4;
  f32x4 acc[4][4];
  #pragma unroll
  for (int mi = 0; mi < 4; mi++)
    #pragma unroll
    for (int ni = 0; ni < 4; ni++) acc[mi][ni] = (f32x4){0.f, 0.f, 0.f, 0.f};
  #pragma unroll
  for (int kk = 0; kk < 4; kk++){
    int k0 = kk * 32 + g * 8;
    bf16x8 af[4], bfr[4];
    #pragma unroll
    for (int mi = 0; mi < 4; mi++) af[mi] = ldFrag(As, wm * 64 + mi * 16 + c16, k0);
    #pragma unroll
    for (int ni = 0; ni < 4; ni++) bfr[ni] = ldFrag(Bs, wn * 64 + ni * 16 + c16, k0);
    #pragma unroll
    for (int mi = 0; mi < 4; mi++)
      #pragma unroll
      for (int ni = 0; ni < 4; ni++)
        acc[mi][ni] = __builtin_amdgcn_mfma_f32_16x16x32_bf16(af[mi], bfr[ni], acc[mi][ni], 0, 0, 0);
  }
  u16* dst; int ld, cofs;
  if (cb == 0){ dst = qB;  ld = 128; cofs = 0; }
  else if (cb == 1){ dst = xrB; ld = 128; cofs = 0; }
  else { dst = kvhB; ld = 384; cofs = (cb - 2) * 128; }
  float bias[4];
  #pragma unroll
  for (int ni = 0; ni < 4; ni++) bias[ni] = bcat[cb * 128 + wn * 64 + ni * 16 + c16];
  #pragma unroll
  for (int mi = 0; mi < 4; mi++){
    #pragma unroll
    for (int r = 0; r < 4; r++){
      int row = row0 + wm * 64 + mi * 16 + g * 4 + r;
      if (row < N){
        #pragma unroll
        for (int ni = 0; ni < 4; ni++)
          dst[(size_t)row * ld + cofs + wn * 64 + ni * 16 + c16] = f2bf(acc[mi][ni][r] + bias[ni]);
      }
    }
  }
}

// ---------- edge pass: half-wave per edge (2 edges/iter), 4 dims/lane ----------
// lanes 0-31 process even-position edges, lanes 32-63 odd-position; merge via shfl_xor(.,32).
__global__ __launch_bounds__(256) void k_edge(const u16* __restrict__ qB, const u16* __restrict__ xrB,
    const u16* __restrict__ kvhB,
    const int* __restrict__ csr, const int* __restrict__ rowptr, const float* __restrict__ dinv,
    const float* __restrict__ bgcn, const float* __restrict__ wbeta,
    const float* __restrict__ lng, const float* __restrict__ lnb,
    const float* __restrict__ lwp, const float* __restrict__ gwp,
    float* __restrict__ xn, u16* __restrict__ xnB, int N){
  int lane = threadIdx.x & 63;
  int half = lane >> 5;
  int li = lane & 31;
  int d0 = li * 4;                      // dims d0..d0+3; head = li>>3 (8 lanes/head)
  int n = blockIdx.x * 4 + (threadIdx.x >> 6);
  if (n >= N) return;
  int ro = rowptr[n], re = rowptr[n + 1];
  uint2 qu = *(const uint2*)(qB + (size_t)n * 128 + d0);
  float q0 = bf2f_lo(qu.x), q1 = bf2f_hi(qu.x), q2 = bf2f_lo(qu.y), q3 = bf2f_hi(qu.y);
  float av0 = 0, av1 = 0, av2 = 0, av3 = 0;
  float ah0 = 0, ah1 = 0, ah2 = 0, ah3 = 0;
  float den = 0;
  const float SC = 0.17677669529663687f;  // 1/sqrt(32)
  for (int e = ro + half; e < re; e += 2){
    int s = csr[e];
    const u16* fb = kvhB + (size_t)s * 384;
    uint2 ku = *(const uint2*)(fb + d0);
    uint2 vu = *(const uint2*)(fb + 128 + d0);
    uint2 hu = *(const uint2*)(fb + 256 + d0);
    float dv = dinv[s];
    float part = q0 * bf2f_lo(ku.x) + q1 * bf2f_hi(ku.x)
               + q2 * bf2f_lo(ku.y) + q3 * bf2f_hi(ku.y);
    part += __shfl_xor(part, 1);        // 8-lane head group
    part += __shfl_xor(part, 2);
    part += __shfl_xor(part, 4);
    float p = __expf(part * SC);
    av0 += p * bf2f_lo(vu.x); av1 += p * bf2f_hi(vu.x);
    av2 += p * bf2f_lo(vu.y); av3 += p * bf2f_hi(vu.y);
    ah0 += dv * bf2f_lo(hu.x); ah1 += dv * bf2f_hi(hu.x);
    ah2 += dv * bf2f_lo(hu.y); ah3 += dv * bf2f_hi(hu.y);
    den += p;
  }
  // merge halves (both halves end with identical totals)
  den += __shfl_xor(den, 32);
  av0 += __shfl_xor(av0, 32); av1 += __shfl_xor(av1, 32);
  av2 += __shfl_xor(av2, 32); av3 += __shfl_xor(av3, 32);
  ah0 += __shfl_xor(ah0, 32); ah1 += __shfl_xor(ah1, 32);
  ah2 += __shfl_xor(ah2, 32); ah3 += __shfl_xor(ah3, 32);
  float inv_den = den > 0 ? 1.0f / den : 0.0f;
  float at0 = av0 * inv_den, at1 = av1 * inv_den, at2 = av2 * inv_den, at3 = av3 * inv_den;
  uint2 xru = *(const uint2*)(xrB + (size_t)n * 128 + d0);
  float xr0 = bf2f_lo(xru.x), xr1 = bf2f_hi(xru.x), xr2 = bf2f_lo(xru.y), xr3 = bf2f_hi(xru.y);
  float4 wb0 = *(const float4*)(wbeta + d0);
  float4 wb1 = *(const float4*)(wbeta + 128 + d0);
  float4 wb2 = *(const float4*)(wbeta + 256 + d0);
  float z = at0 * wb0.x + at1 * wb0.y + at2 * wb0.z + at3 * wb0.w
          + xr0 * wb1.x + xr1 * wb1.y + xr2 * wb1.z + xr3 * wb1.w
          + (at0 - xr0) * wb2.x + (at1 - xr1) * wb2.y
          + (at2 - xr2) * wb2.z + (at3 - xr3) * wb2.w;
  z += __shfl_xor(z, 1); z += __shfl_xor(z, 2); z += __shfl_xor(z, 4);
  z += __shfl_xor(z, 8); z += __shfl_xor(z, 16);
  float beta = 1.0f / (1.0f + __expf(-z));
  float dn = dinv[n];
  float4 bg = *(const float4*)(bgcn + d0);
  float l0 = dn * ah0 + bg.x, l1 = dn * ah1 + bg.y, l2 = dn * ah2 + bg.z, l3 = dn * ah3 + bg.w;
  float lw = lwp[0], gw = gwp[0];
  float ib = 1.0f - beta;
  float t0 = 2.0f * (lw * l0 + gw * (beta * xr0 + ib * at0));
  float t1 = 2.0f * (lw * l1 + gw * (beta * xr1 + ib * at1));
  float t2 = 2.0f * (lw * l2 + gw * (beta * xr2 + ib * at2));
  float t3 = 2.0f * (lw * l3 + gw * (beta * xr3 + ib * at3));
  float s = t0 + t1 + t2 + t3;
  float sq = t0*t0 + t1*t1 + t2*t2 + t3*t3;
  s += __shfl_xor(s, 1);  sq += __shfl_xor(sq, 1);
  s += __shfl_xor(s, 2);  sq += __shfl_xor(sq, 2);
  s += __shfl_xor(s, 4);  sq += __shfl_xor(sq, 4);
  s += __shfl_xor(s, 8);  sq += __shfl_xor(sq, 8);
  s += __shfl_xor(s, 16); sq += __shfl_xor(sq, 16);
  float mu = s * (1.0f / 128.0f);
  float var = sq * (1.0f / 128.0f) - mu * mu;
  float inv = rsqrtf(var + 1e-5f);
  if (half == 0){
    float4 gm = *(const float4*)(lng + d0);
    float4 bt = *(const float4*)(lnb + d0);
    float o0 = (t0 - mu) * inv * gm.x + bt.x;
    float o1 = (t1 - mu) * inv * gm.y + bt.y;
    float o2 = (t2 - mu) * inv * gm.z + bt.z;
    float o3 = (t3 - mu) * inv * gm.w + bt.w;
    *(float4*)(xn + (size_t)n * 128 + d0) = make_float4(o0, o1, o2, o3);
    uint2 pk;
    pk.x = (u32)f2bf(o0) | ((u32)f2bf(o1) << 16);
    pk.y = (u32)f2bf(o2) | ((u32)f2bf(o3) << 16);
    *(uint2*)(xnB + (size_t)n * 128 + d0) = pk;
  }
}

// ---------- FFN1 (MFMA): hid(bf16) = relu(xnB @ w1 + b1) ----------
__global__ __launch_bounds__(256) void k_ffn1(const u16* __restrict__ xnB, const u16* __restrict__ w1T,
    const float* __restrict__ b1, u16* __restrict__ hid, int N){
  __shared__ u16 As[128 * 128];
  __shared__ u16 Bs[128 * 128];
  int row0 = blockIdx.x * 128, cb = blockIdx.y;
  stageTile(xnB, 128, row0, N, 0, As);
  stageTile(w1T, 128, cb * 128, 1 << 30, 0, Bs);
  __syncthreads();
  int t = threadIdx.x, l = t & 63, w = t >> 6;
  int wm = w >> 1, wn = w & 1;
  int c16 = l & 15, g = l >> 4;
  f32x4 acc[4][4];
  #pragma unroll
  for (int mi = 0; mi < 4; mi++)
    #pragma unroll
    for (int ni = 0; ni < 4; ni++) acc[mi][ni] = (f32x4){0.f, 0.f, 0.f, 0.f};
  #pragma unroll
  for (int kk = 0; kk < 4; kk++){
    int k0 = kk * 32 + g * 8;
    bf16x8 af[4], bfr[4];
    #pragma unroll
    for (int mi = 0; mi < 4; mi++) af[mi] = ldFrag(As, wm * 64 + mi * 16 + c16, k0);
    #pragma unroll
    for (int ni = 0; ni < 4; ni++) bfr[ni] = ldFrag(Bs, wn * 64 + ni * 16 + c16, k0);
    #pragma unroll
    for (int mi = 0; mi < 4; mi++)
      #pragma unroll
      for (int ni = 0; ni < 4; ni++)
        acc[mi][ni] = __builtin_amdgcn_mfma_f32_16x16x32_bf16(af[mi], bfr[ni], acc[mi][ni], 0, 0, 0);
  }
  float bias[4];
  #pragma unroll
  for (int ni = 0; ni < 4; ni++) bias[ni] = b1[cb * 128 + wn * 64 + ni * 16 + c16];
  #pragma unroll
  for (int mi = 0; mi < 4; mi++){
    #pragma unroll
    for (int r = 0; r < 4; r++){
      int row = row0 + wm * 64 + mi * 16 + g * 4 + r;
      if (row < N){
        #pragma unroll
        for (int ni = 0; ni < 4; ni++)
          hid[(size_t)row * 256 + cb * 128 + wn * 64 + ni * 16 + c16] =
              f2bf(fmaxf(acc[mi][ni][r] + bias[ni], 0.0f));
      }
    }
  }
}

// ---------- FFN2 (MFMA) + residual + LN2 -> out (f32, in place over xn) ----------
__global__ __launch_bounds__(256) void k_ffn2(const u16* __restrict__ hid, const u16* __restrict__ w2T,
    const float* __restrict__ b2, const float* __restrict__ xnf,
    const float* __restrict__ g2, const float* __restrict__ bt2,
    float* __restrict__ out, int N){
  __shared__ u16 As[128 * 128];
  __shared__ u16 Bs[128 * 128];
  int row0 = blockIdx.x * 128;
  int t = threadIdx.x, l = t & 63, w = t >> 6;
  int c16 = l & 15, g = l >> 4;
  f32x4 acc[2][8];
  #pragma unroll
  for (int mi = 0; mi < 2; mi++)
    #pragma unroll
    for (int ni = 0; ni < 8; ni++) acc[mi][ni] = (f32x4){0.f, 0.f, 0.f, 0.f};
  for (int kc = 0; kc < 2; kc++){
    if (kc) __syncthreads();
    stageTile(hid, 256, row0, N, kc * 128, As);
    stageTile(w2T, 256, 0, 1 << 30, kc * 128, Bs);
    __syncthreads();
    #pragma unroll
    for (int kk = 0; kk < 4; kk++){
      int k0 = kk * 32 + g * 8;
      bf16x8 af[2], bfr[8];
      #pragma unroll
      for (int mi = 0; mi < 2; mi++) af[mi] = ldFrag(As, w * 32 + mi * 16 + c16, k0);
      #pragma unroll
      for (int ni = 0; ni < 8; ni++) bfr[ni] = ldFrag(Bs, ni * 16 + c16, k0);
      #pragma unroll
      for (int mi = 0; mi < 2; mi++)
        #pragma unroll
        for (int ni = 0; ni < 8; ni++)
          acc[mi][ni] = __builtin_amdgcn_mfma_f32_16x16x32_bf16(af[mi], bfr[ni], acc[mi][ni], 0, 0, 0);
    }
  }
  float b2c[8], g2c[8], btc[8];
  #pragma unroll
  for (int ni = 0; ni < 8; ni++){
    int col = ni * 16 + c16;
    b2c[ni] = b2[col]; g2c[ni] = g2[col]; btc[ni] = bt2[col];
  }
  #pragma unroll
  for (int mi = 0; mi < 2; mi++){
    #pragma unroll
    for (int r = 0; r < 4; r++){
      int row = row0 + w * 32 + mi * 16 + g * 4 + r;
      int rc = row < N ? row : N - 1;
      float z[8]; float s = 0.f, sq = 0.f;
      #pragma unroll
      for (int ni = 0; ni < 8; ni++){
        z[ni] = acc[mi][ni][r] + b2c[ni] + xnf[(size_t)rc * 128 + ni * 16 + c16];
        s += z[ni]; sq += z[ni] * z[ni];
      }
      s += __shfl_xor(s, 1); sq += __shfl_xor(sq, 1);
      s += __shfl_xor(s, 2); sq += __shfl_xor(sq, 2);
      s += __shfl_xor(s, 4); sq += __shfl_xor(sq, 4);
      s += __shfl_xor(s, 8); sq += __shfl_xor(sq, 8);
      float mu = s * (1.0f / 128.0f);
      float var = sq * (1.0f / 128.0f) - mu * mu;
      float inv = rsqrtf(var + 1e-5f);
      if (row < N){
        #pragma unroll
        for (int ni = 0; ni < 8; ni++)
          out[(size_t)row * 128 + ni * 16 + c16] = (z[ni] - mu) * inv * g2c[ni] + btc[ni];
      }
    }
  }
}

extern "C" void kernel_launch(void* const* d_in, const int* in_sizes, int n_in,
                              void* d_out, int out_size, void* d_ws, size_t ws_size,
                              hipStream_t stream){
  const float* x      = (const float*)d_in[0];
  const int*   ei     = (const int*)d_in[1];
  const float* w_gcn  = (const float*)d_in[2];
  const float* b_gcn  = (const float*)d_in[3];
  const float* w_q    = (const float*)d_in[4];
  const float* b_q    = (const float*)d_in[5];
  const float* w_k    = (const float*)d_in[6];
  const float* b_k    = (const float*)d_in[7];
  const float* w_v    = (const float*)d_in[8];
  const float* b_v    = (const float*)d_in[9];
  const float* w_skip = (const float*)d_in[10];
  const float* b_skip = (const float*)d_in[11];
  const float* w_beta = (const float*)d_in[12];
  const float* ln1_g  = (const float*)d_in[13];
  const float* ln1_b  = (const float*)d_in[14];
  const float* ln2_g  = (const float*)d_in[15];
  const float* ln2_b  = (const float*)d_in[16];
  const float* w1     = (const float*)d_in[17];
  const float* b1     = (const float*)d_in[18];
  const float* w2     = (const float*)d_in[19];
  const float* b2     = (const float*)d_in[20];
  const float* lw     = (const float*)d_in[21];
  const float* gw     = (const float*)d_in[22];
  int N = in_sizes[0] / 128;
  int E = in_sizes[1] / 2;
  float* outf = (float*)d_out;
  float* xn   = (float*)d_out;   // xn lives in d_out; ffn2 reads-then-overwrites per row

  char* ws = (char*)d_ws;
  size_t off = 0;
  auto alloc = [&](size_t bytes) -> char* {
    char* p = ws + off; off += (bytes + 255) & ~(size_t)255; return p;
  };
  u16* kvhB   = (u16*)alloc((size_t)N * 384 * 2);   // [k | v | h] bf16; aliased by hid after edge
  u16* xrB    = (u16*)alloc((size_t)N * 128 * 2);
  u16* qB     = (u16*)alloc((size_t)N * 128 * 2);
  u16* xB     = (u16*)alloc((size_t)N * 128 * 2);   // aliased by xnB after gemm1
  int* csr    = (int*)alloc((size_t)E * 4);
  int* deg    = (int*)alloc((size_t)N * 4);
  int* rowptr = (int*)alloc((size_t)(N + 1) * 4);
  int* fill   = (int*)alloc((size_t)N * 4);
  float* dinv = (float*)alloc((size_t)N * 4);
  int NB = (N + 1023) >> 10;
  int* bsum   = (int*)alloc((size_t)NB * 4);
  int* boff   = (int*)alloc((size_t)NB * 4);
  u16* WcatT  = (u16*)alloc((size_t)640 * 128 * 2);
  float* bcat = (float*)alloc((size_t)640 * 4);
  u16* w1T    = (u16*)alloc((size_t)256 * 128 * 2);
  u16* w2T    = (u16*)alloc((size_t)128 * 256 * 2);
  u16* hid    = kvhB;            // alias: kvhB dead after k_edge (N*256*2 <= N*384*2)
  u16* xnB    = xB;              // alias: xB dead after k_gemm1

  if (off > ws_size) return;     // bail cleanly if workspace too small

  hipMemsetAsync(deg, 0, (size_t)N * 4, stream);
  hipMemsetAsync(fill, 0, (size_t)N * 4, stream);

  k_prep_all<<<576, 256, 0, stream>>>(w_q, b_q, w_skip, b_skip, w_k, b_k, w_v, b_v, w_gcn,
                                      w1, w2, WcatT, bcat, w1T, w2T);
  k_cvt<<<(N * 128 / 4 + 255) / 256, 256, 0, stream>>>(x, xB, N * 128);
  k_hist<<<(E + 255) / 256, 256, 0, stream>>>(ei, E, deg);
  k_scan_a<<<NB, 256, 0, stream>>>(deg, N, bsum);
  k_scan_b<<<1, 1024, 0, stream>>>(bsum, NB, boff);
  k_scan_c<<<NB, 256, 0, stream>>>(deg, N, E, boff, rowptr);
  k_dinv<<<(N + 255) / 256, 256, 0, stream>>>(deg, N, dinv);
  k_csr<<<(E + 255) / 256, 256, 0, stream>>>(ei, E, rowptr, fill, csr);

  int MB = (N + 127) / 128;
  dim3 g1(MB, 5);
  k_gemm1<<<g1, 256, 0, stream>>>(xB, WcatT, bcat, qB, xrB, kvhB, N);
  k_edge<<<(N + 3) / 4, 256, 0, stream>>>(qB, xrB, kvhB, csr, rowptr, dinv, b_gcn, w_beta,
                                          ln1_g, ln1_b, lw, gw, xn, xnB, N);
  dim3 f1(MB, 2);
  k_ffn1<<<f1, 256, 0, stream>>>(xnB, w1T, b1, hid, N);
  k_ffn2<<<MB, 256, 0, stream>>>(hid, w2T, b2, xn, ln2_g, ln2_b, outf, N);
}

// Round 8
// 455.334 us; speedup vs baseline: 1.1062x; 1.0382x over previous
//
#include <hip/hip_runtime.h>

typedef unsigned int u32;
typedef unsigned short u16;
typedef __attribute__((ext_vector_type(8))) short bf16x8;
typedef __attribute__((ext_vector_type(4))) float f32x4;

__device__ __forceinline__ float bf2f(u16 u){ return __uint_as_float(((u32)u) << 16); }
__device__ __forceinline__ float bf2f_lo(u32 u){ return __uint_as_float(u << 16); }
__device__ __forceinline__ float bf2f_hi(u32 u){ return __uint_as_float(u & 0xffff0000u); }
__device__ __forceinline__ u16 f2bf(float f){
  u32 x = __float_as_uint(f);
  return (u16)((x + 0x7fffu + ((x >> 16) & 1u)) >> 16);  // RNE
}

// ---------- prep: WcatT[640][128] ([q|skip|k|v|gcn], [outcol][k]) + bcat, w1T, w2T (bf16) ----------
__global__ void k_prep_all(const float* wq, const float* bq, const float* wsk, const float* bsk,
                           const float* wk, const float* bk, const float* wv, const float* bv,
                           const float* wg, const float* w1, const float* w2,
                           u16* WcatT, float* bcat, u16* w1T, u16* w2T){
  int idx = blockIdx.x * 256 + threadIdx.x;
  if (idx < 640 * 128){
    int col = idx >> 7, k = idx & 127;
    int blk = col >> 7, c = col & 127;
    const float* w = (blk==0)?wq:(blk==1)?wsk:(blk==2)?wk:(blk==3)?wv:wg;
    WcatT[idx] = f2bf(w[k * 128 + c]);
    if (k == 0){
      const float* b = (blk==0)?bq:(blk==1)?bsk:(blk==2)?bk:(blk==3)?bv:nullptr;
      bcat[col] = b ? b[c] : 0.0f;   // gcn bias added after aggregation
    }
  } else if (idx < 640*128 + 256*128){
    int j = idx - 640*128; int c = j >> 7, k = j & 127;
    w1T[j] = f2bf(w1[k * 256 + c]);
  } else if (idx < 640*128 + 256*128 + 128*256){
    int j = idx - (640*128 + 256*128); int c = j >> 8, k = j & 255;
    w2T[j] = f2bf(w2[k * 128 + c]);
  }
}

// ---------- graph prep (edge_index int32: src=ei[e], dst=ei[E+e]) ----------
__global__ void k_hist(const int* __restrict__ ei, int E, int* __restrict__ deg){
  int e = blockIdx.x * 256 + threadIdx.x;
  if (e >= E) return;
  atomicAdd(&deg[ei[E + e]], 1);
}
__global__ void k_scan_a(const int* __restrict__ deg, int N, int* __restrict__ bsum){
  __shared__ int sh[256];
  int b = blockIdx.x, t = threadIdx.x;
  int base = b * 1024 + t * 4, s = 0;
  #pragma unroll
  for (int j = 0; j < 4; j++){ int i = base + j; if (i < N) s += deg[i]; }
  sh[t] = s; __syncthreads();
  for (int off = 128; off > 0; off >>= 1){ if (t < off) sh[t] += sh[t + off]; __syncthreads(); }
  if (t == 0) bsum[b] = sh[0];
}
__global__ void k_scan_b(const int* __restrict__ bsum, int NB, int* __restrict__ boff){
  __shared__ int sh[1024];
  int t = threadIdx.x;
  int self = (t < NB) ? bsum[t] : 0;
  sh[t] = self; __syncthreads();
  for (int off = 1; off < 1024; off <<= 1){
    int v = sh[t]; int add = (t >= off) ? sh[t - off] : 0;
    __syncthreads(); sh[t] = v + add; __syncthreads();
  }
  if (t < NB) boff[t] = sh[t] - self;
}
// scan_c also emits dinv (deg already in registers)
__global__ void k_scan_c(const int* __restrict__ deg, int N, int E,
                         const int* __restrict__ boff, int* __restrict__ rowptr,
                         float* __restrict__ dinv){
  __shared__ int sh[256];
  int b = blockIdx.x, t = threadIdx.x;
  int base = b * 1024 + t * 4;
  int d[4]; int ts = 0;
  #pragma unroll
  for (int j = 0; j < 4; j++){ int i = base + j; d[j] = (i < N) ? deg[i] : 0; ts += d[j]; }
  sh[t] = ts; __syncthreads();
  for (int off = 1; off < 256; off <<= 1){
    int v = sh[t]; int add = (t >= off) ? sh[t - off] : 0;
    __syncthreads(); sh[t] = v + add; __syncthreads();
  }
  int excl = sh[t] - ts + boff[b];
  #pragma unroll
  for (int j = 0; j < 4; j++){
    int i = base + j;
    if (i < N){
      rowptr[i] = excl;
      dinv[i] = d[j] > 0 ? rsqrtf((float)d[j]) : 0.0f;
    }
    excl += d[j];
  }
  if (b == 0 && t == 0) rowptr[N] = E;
}
__global__ void k_csr(const int* __restrict__ ei, int E,
                      const int* __restrict__ rowptr, int* __restrict__ fill, int* __restrict__ csr){
  int e = blockIdx.x * 256 + threadIdx.x;
  if (e >= E) return;
  int d = ei[E + e];
  int pos = rowptr[d] + atomicAdd(&fill[d], 1);
  csr[pos] = ei[e];
}

// ---------- MFMA tile helpers: 128 rows x 128 halves, XOR-swizzled LDS ----------
__device__ __forceinline__ void stageTile(const u16* __restrict__ g, int ldg, int row0, int rclamp,
                                          int kofs, u16* lds){
  int t = threadIdx.x;
  #pragma unroll
  for (int p = 0; p < 8; p++){
    int chunk = p * 256 + t;
    int r = chunk >> 4;
    int cs = (chunk & 15) << 3;
    int rg = row0 + r; if (rg >= rclamp) rg = rclamp - 1;
    bf16x8 v = *(const bf16x8*)(g + (size_t)rg * ldg + kofs + cs);
    *(bf16x8*)(lds + r * 128 + (cs ^ ((r & 7) << 3))) = v;
  }
}
// stage from f32 source with inline bf16 conversion (same RNE as k_cvt did)
__device__ __forceinline__ void stageTileF32(const float* __restrict__ g, int ldg, int row0,
                                             int rclamp, u16* lds){
  int t = threadIdx.x;
  #pragma unroll
  for (int p = 0; p < 8; p++){
    int chunk = p * 256 + t;
    int r = chunk >> 4;
    int cs = (chunk & 15) << 3;
    int rg = row0 + r; if (rg >= rclamp) rg = rclamp - 1;
    const float* src = g + (size_t)rg * ldg + cs;
    float4 a = *(const float4*)(src);
    float4 b = *(const float4*)(src + 4);
    u16* dst = lds + r * 128 + (cs ^ ((r & 7) << 3));
    ushort4 lo; lo.x = f2bf(a.x); lo.y = f2bf(a.y); lo.z = f2bf(a.z); lo.w = f2bf(a.w);
    ushort4 hi; hi.x = f2bf(b.x); hi.y = f2bf(b.y); hi.z = f2bf(b.z); hi.w = f2bf(b.w);
    *(ushort4*)dst = lo;
    *(ushort4*)(dst + 4) = hi;
  }
}
__device__ __forceinline__ bf16x8 ldFrag(const u16* lds, int r, int k0){
  return *(const bf16x8*)(lds + r * 128 + (k0 ^ ((r & 7) << 3)));
}

// ---------- GEMM1 (MFMA, col-loop): [q | xr | k,v,h] bf16 = x @ WcatT^T + bcat ----------
__global__ __launch_bounds__(256) void k_gemm1(const float* __restrict__ x, const u16* __restrict__ WcatT,
    const float* __restrict__ bcat, u16* __restrict__ qB, u16* __restrict__ xrB,
    u16* __restrict__ kvhB, int N){
  __shared__ u16 As[128 * 128];
  __shared__ u16 Bs[128 * 128];
  int row0 = blockIdx.x * 128;
  stageTileF32(x, 128, row0, N, As);     // A staged ONCE for all 5 col-blocks
  int t = threadIdx.x, l = t & 63, w = t >> 6;
  int wm = w >> 1, wn = w & 1;
  int c16 = l & 15, g = l >> 4;
  for (int cb = 0; cb < 5; cb++){
    stageTile(WcatT, 128, cb * 128, 1 << 30, 0, Bs);
    __syncthreads();
    f32x4 acc[4][4];
    #pragma unroll
    for (int mi = 0; mi < 4; mi++)
      #pragma unroll
      for (int ni = 0; ni < 4; ni++) acc[mi][ni] = (f32x4){0.f, 0.f, 0.f, 0.f};
    #pragma unroll
    for (int kk = 0; kk < 4; kk++){
      int k0 = kk * 32 + g * 8;
      bf16x8 af[4], bfr[4];
      #pragma unroll
      for (int mi = 0; mi < 4; mi++) af[mi] = ldFrag(As, wm * 64 + mi * 16 + c16, k0);
      #pragma unroll
      for (int ni = 0; ni < 4; ni++) bfr[ni] = ldFrag(Bs, wn * 64 + ni * 16 + c16, k0);
      #pragma unroll
      for (int mi = 0; mi < 4; mi++)
        #pragma unroll
        for (int ni = 0; ni < 4; ni++)
          acc[mi][ni] = __builtin_amdgcn_mfma_f32_16x16x32_bf16(af[mi], bfr[ni], acc[mi][ni], 0, 0, 0);
    }
    u16* dst; int ld, cofs;
    if (cb == 0){ dst = qB;  ld = 128; cofs = 0; }
    else if (cb == 1){ dst = xrB; ld = 128; cofs = 0; }
    else { dst = kvhB; ld = 384; cofs = (cb - 2) * 128; }
    float bias[4];
    #pragma unroll
    for (int ni = 0; ni < 4; ni++) bias[ni] = bcat[cb * 128 + wn * 64 + ni * 16 + c16];
    #pragma unroll
    for (int mi = 0; mi < 4; mi++){
      #pragma unroll
      for (int r = 0; r < 4; r++){
        int row = row0 + wm * 64 + mi * 16 + g * 4 + r;
        if (row < N){
          #pragma unroll
          for (int ni = 0; ni < 4; ni++)
            dst[(size_t)row * ld + cofs + wn * 64 + ni * 16 + c16] = f2bf(acc[mi][ni][r] + bias[ni]);
        }
      }
    }
    __syncthreads();   // Bs consumed; safe to restage next col-block
  }
}

// ---------- edge pass: half-wave per edge (2 edges/iter), 4 dims/lane; bf16 output only ----------
__global__ __launch_bounds__(256) void k_edge(const u16* __restrict__ qB, const u16* __restrict__ xrB,
    const u16* __restrict__ kvhB,
    const int* __restrict__ csr, const int* __restrict__ rowptr, const float* __restrict__ dinv,
    const float* __restrict__ bgcn, const float* __restrict__ wbeta,
    const float* __restrict__ lng, const float* __restrict__ lnb,
    const float* __restrict__ lwp, const float* __restrict__ gwp,
    u16* __restrict__ xnB, int N){
  int lane = threadIdx.x & 63;
  int half = lane >> 5;
  int li = lane & 31;
  int d0 = li * 4;                      // dims d0..d0+3; head = li>>3 (8 lanes/head)
  int n = blockIdx.x * 4 + (threadIdx.x >> 6);
  if (n >= N) return;
  int ro = rowptr[n], re = rowptr[n + 1];
  uint2 qu = *(const uint2*)(qB + (size_t)n * 128 + d0);
  float q0 = bf2f_lo(qu.x), q1 = bf2f_hi(qu.x), q2 = bf2f_lo(qu.y), q3 = bf2f_hi(qu.y);
  float av0 = 0, av1 = 0, av2 = 0, av3 = 0;
  float ah0 = 0, ah1 = 0, ah2 = 0, ah3 = 0;
  float den = 0;
  const float SC = 0.17677669529663687f;  // 1/sqrt(32)
  for (int e = ro + half; e < re; e += 2){
    int s = csr[e];
    const u16* fb = kvhB + (size_t)s * 384;
    uint2 ku = *(const uint2*)(fb + d0);
    uint2 vu = *(const uint2*)(fb + 128 + d0);
    uint2 hu = *(const uint2*)(fb + 256 + d0);
    float dv = dinv[s];
    float part = q0 * bf2f_lo(ku.x) + q1 * bf2f_hi(ku.x)
               + q2 * bf2f_lo(ku.y) + q3 * bf2f_hi(ku.y);
    part += __shfl_xor(part, 1);        // 8-lane head group
    part += __shfl_xor(part, 2);
    part += __shfl_xor(part, 4);
    float p = __expf(part * SC);
    av0 += p * bf2f_lo(vu.x); av1 += p * bf2f_hi(vu.x);
    av2 += p * bf2f_lo(vu.y); av3 += p * bf2f_hi(vu.y);
    ah0 += dv * bf2f_lo(hu.x); ah1 += dv * bf2f_hi(hu.x);
    ah2 += dv * bf2f_lo(hu.y); ah3 += dv * bf2f_hi(hu.y);
    den += p;
  }
  // merge halves (both halves end with identical totals)
  den += __shfl_xor(den, 32);
  av0 += __shfl_xor(av0, 32); av1 += __shfl_xor(av1, 32);
  av2 += __shfl_xor(av2, 32); av3 += __shfl_xor(av3, 32);
  ah0 += __shfl_xor(ah0, 32); ah1 += __shfl_xor(ah1, 32);
  ah2 += __shfl_xor(ah2, 32); ah3 += __shfl_xor(ah3, 32);
  float inv_den = den > 0 ? 1.0f / den : 0.0f;
  float at0 = av0 * inv_den, at1 = av1 * inv_den, at2 = av2 * inv_den, at3 = av3 * inv_den;
  uint2 xru = *(const uint2*)(xrB + (size_t)n * 128 + d0);
  float xr0 = bf2f_lo(xru.x), xr1 = bf2f_hi(xru.x), xr2 = bf2f_lo(xru.y), xr3 = bf2f_hi(xru.y);
  float4 wb0 = *(const float4*)(wbeta + d0);
  float4 wb1 = *(const float4*)(wbeta + 128 + d0);
  float4 wb2 = *(const float4*)(wbeta + 256 + d0);
  float z = at0 * wb0.x + at1 * wb0.y + at2 * wb0.z + at3 * wb0.w
          + xr0 * wb1.x + xr1 * wb1.y + xr2 * wb1.z + xr3 * wb1.w
          + (at0 - xr0) * wb2.x + (at1 - xr1) * wb2.y
          + (at2 - xr2) * wb2.z + (at3 - xr3) * wb2.w;
  z += __shfl_xor(z, 1); z += __shfl_xor(z, 2); z += __shfl_xor(z, 4);
  z += __shfl_xor(z, 8); z += __shfl_xor(z, 16);
  float beta = 1.0f / (1.0f + __expf(-z));
  float dn = dinv[n];
  float4 bg = *(const float4*)(bgcn + d0);
  float l0 = dn * ah0 + bg.x, l1 = dn * ah1 + bg.y, l2 = dn * ah2 + bg.z, l3 = dn * ah3 + bg.w;
  float lw = lwp[0], gw = gwp[0];
  float ib = 1.0f - beta;
  float t0 = 2.0f * (lw * l0 + gw * (beta * xr0 + ib * at0));
  float t1 = 2.0f * (lw * l1 + gw * (beta * xr1 + ib * at1));
  float t2 = 2.0f * (lw * l2 + gw * (beta * xr2 + ib * at2));
  float t3 = 2.0f * (lw * l3 + gw * (beta * xr3 + ib * at3));
  float s = t0 + t1 + t2 + t3;
  float sq = t0*t0 + t1*t1 + t2*t2 + t3*t3;
  s += __shfl_xor(s, 1);  sq += __shfl_xor(sq, 1);
  s += __shfl_xor(s, 2);  sq += __shfl_xor(sq, 2);
  s += __shfl_xor(s, 4);  sq += __shfl_xor(sq, 4);
  s += __shfl_xor(s, 8);  sq += __shfl_xor(sq, 8);
  s += __shfl_xor(s, 16); sq += __shfl_xor(sq, 16);
  float mu = s * (1.0f / 128.0f);
  float var = sq * (1.0f / 128.0f) - mu * mu;
  float inv = rsqrtf(var + 1e-5f);
  if (half == 0){
    float4 gm = *(const float4*)(lng + d0);
    float4 bt = *(const float4*)(lnb + d0);
    float o0 = (t0 - mu) * inv * gm.x + bt.x;
    float o1 = (t1 - mu) * inv * gm.y + bt.y;
    float o2 = (t2 - mu) * inv * gm.z + bt.z;
    float o3 = (t3 - mu) * inv * gm.w + bt.w;
    uint2 pk;
    pk.x = (u32)f2bf(o0) | ((u32)f2bf(o1) << 16);
    pk.y = (u32)f2bf(o2) | ((u32)f2bf(o3) << 16);
    *(uint2*)(xnB + (size_t)n * 128 + d0) = pk;
  }
}

// ---------- FFN1 (MFMA): hid(bf16) = relu(xnB @ w1 + b1) ----------
__global__ __launch_bounds__(256) void k_ffn1(const u16* __restrict__ xnB, const u16* __restrict__ w1T,
    const float* __restrict__ b1, u16* __restrict__ hid, int N){
  __shared__ u16 As[128 * 128];
  __shared__ u16 Bs[128 * 128];
  int row0 = blockIdx.x * 128, cb = blockIdx.y;
  stageTile(xnB, 128, row0, N, 0, As);
  stageTile(w1T, 128, cb * 128, 1 << 30, 0, Bs);
  __syncthreads();
  int t = threadIdx.x, l = t & 63, w = t >> 6;
  int wm = w >> 1, wn = w & 1;
  int c16 = l & 15, g = l >> 4;
  f32x4 acc[4][4];
  #pragma unroll
  for (int mi = 0; mi < 4; mi++)
    #pragma unroll
    for (int ni = 0; ni < 4; ni++) acc[mi][ni] = (f32x4){0.f, 0.f, 0.f, 0.f};
  #pragma unroll
  for (int kk = 0; kk < 4; kk++){
    int k0 = kk * 32 + g * 8;
    bf16x8 af[4], bfr[4];
    #pragma unroll
    for (int mi = 0; mi < 4; mi++) af[mi] = ldFrag(As, wm * 64 + mi * 16 + c16, k0);
    #pragma unroll
    for (int ni = 0; ni < 4; ni++) bfr[ni] = ldFrag(Bs, wn * 64 + ni * 16 + c16, k0);
    #pragma unroll
    for (int mi = 0; mi < 4; mi++)
      #pragma unroll
      for (int ni = 0; ni < 4; ni++)
        acc[mi][ni] = __builtin_amdgcn_mfma_f32_16x16x32_bf16(af[mi], bfr[ni], acc[mi][ni], 0, 0, 0);
  }
  float bias[4];
  #pragma unroll
  for (int ni = 0; ni < 4; ni++) bias[ni] = b1[cb * 128 + wn * 64 + ni * 16 + c16];
  #pragma unroll
  for (int mi = 0; mi < 4; mi++){
    #pragma unroll
    for (int r = 0; r < 4; r++){
      int row = row0 + wm * 64 + mi * 16 + g * 4 + r;
      if (row < N){
        #pragma unroll
        for (int ni = 0; ni < 4; ni++)
          hid[(size_t)row * 256 + cb * 128 + wn * 64 + ni * 16 + c16] =
              f2bf(fmaxf(acc[mi][ni][r] + bias[ni], 0.0f));
      }
    }
  }
}

// ---------- FFN2 (MFMA) + residual(bf16 xnB) + LN2 -> out ----------
__global__ __launch_bounds__(256) void k_ffn2(const u16* __restrict__ hid, const u16* __restrict__ w2T,
    const float* __restrict__ b2, const u16* __restrict__ xnB,
    const float* __restrict__ g2, const float* __restrict__ bt2,
    float* __restrict__ out, int N){
  __shared__ u16 As[128 * 128];
  __shared__ u16 Bs[128 * 128];
  int row0 = blockIdx.x * 128;
  int t = threadIdx.x, l = t & 63, w = t >> 6;
  int c16 = l & 15, g = l >> 4;
  f32x4 acc[2][8];
  #pragma unroll
  for (int mi = 0; mi < 2; mi++)
    #pragma unroll
    for (int ni = 0; ni < 8; ni++) acc[mi][ni] = (f32x4){0.f, 0.f, 0.f, 0.f};
  for (int kc = 0; kc < 2; kc++){
    if (kc) __syncthreads();
    stageTile(hid, 256, row0, N, kc * 128, As);
    stageTile(w2T, 256, 0, 1 << 30, kc * 128, Bs);
    __syncthreads();
    #pragma unroll
    for (int kk = 0; kk < 4; kk++){
      int k0 = kk * 32 + g * 8;
      bf16x8 af[2], bfr[8];
      #pragma unroll
      for (int mi = 0; mi < 2; mi++) af[mi] = ldFrag(As, w * 32 + mi * 16 + c16, k0);
      #pragma unroll
      for (int ni = 0; ni < 8; ni++) bfr[ni] = ldFrag(Bs, ni * 16 + c16, k0);
      #pragma unroll
      for (int mi = 0; mi < 2; mi++)
        #pragma unroll
        for (int ni = 0; ni < 8; ni++)
          acc[mi][ni] = __builtin_amdgcn_mfma_f32_16x16x32_bf16(af[mi], bfr[ni], acc[mi][ni], 0, 0, 0);
    }
  }
  float b2c[8], g2c[8], btc[8];
  #pragma unroll
  for (int ni = 0; ni < 8; ni++){
    int col = ni * 16 + c16;
    b2c[ni] = b2[col]; g2c[ni] = g2[col]; btc[ni] = bt2[col];
  }
  #pragma unroll
  for (int mi = 0; mi < 2; mi++){
    #pragma unroll
    for (int r = 0; r < 4; r++){
      int row = row0 + w * 32 + mi * 16 + g * 4 + r;
      int rc = row < N ? row : N - 1;
      float z[8]; float s = 0.f, sq = 0.f;
      #pragma unroll
      for (int ni = 0; ni < 8; ni++){
        float xv = bf2f(xnB[(size_t)rc * 128 + ni * 16 + c16]);
        z[ni] = acc[mi][ni][r] + b2c[ni] + xv;
        s += z[ni]; sq += z[ni] * z[ni];
      }
      s += __shfl_xor(s, 1); sq += __shfl_xor(sq, 1);
      s += __shfl_xor(s, 2); sq += __shfl_xor(sq, 2);
      s += __shfl_xor(s, 4); sq += __shfl_xor(sq, 4);
      s += __shfl_xor(s, 8); sq += __shfl_xor(sq, 8);
      float mu = s * (1.0f / 128.0f);
      float var = sq * (1.0f / 128.0f) - mu * mu;
      float inv = rsqrtf(var + 1e-5f);
      if (row < N){
        #pragma unroll
        for (int ni = 0; ni < 8; ni++)
          out[(size_t)row * 128 + ni * 16 + c16] = (z[ni] - mu) * inv * g2c[ni] + btc[ni];
      }
    }
  }
}

extern "C" void kernel_launch(void* const* d_in, const int* in_sizes, int n_in,
                              void* d_out, int out_size, void* d_ws, size_t ws_size,
                              hipStream_t stream){
  const float* x      = (const float*)d_in[0];
  const int*   ei     = (const int*)d_in[1];
  const float* w_gcn  = (const float*)d_in[2];
  const float* b_gcn  = (const float*)d_in[3];
  const float* w_q    = (const float*)d_in[4];
  const float* b_q    = (const float*)d_in[5];
  const float* w_k    = (const float*)d_in[6];
  const float* b_k    = (const float*)d_in[7];
  const float* w_v    = (const float*)d_in[8];
  const float* b_v    = (const float*)d_in[9];
  const float* w_skip = (const float*)d_in[10];
  const float* b_skip = (const float*)d_in[11];
  const float* w_beta = (const float*)d_in[12];
  const float* ln1_g  = (const float*)d_in[13];
  const float* ln1_b  = (const float*)d_in[14];
  const float* ln2_g  = (const float*)d_in[15];
  const float* ln2_b  = (const float*)d_in[16];
  const float* w1     = (const float*)d_in[17];
  const float* b1     = (const float*)d_in[18];
  const float* w2     = (const float*)d_in[19];
  const float* b2     = (const float*)d_in[20];
  const float* lw     = (const float*)d_in[21];
  const float* gw     = (const float*)d_in[22];
  int N = in_sizes[0] / 128;
  int E = in_sizes[1] / 2;
  float* outf = (float*)d_out;

  char* ws = (char*)d_ws;
  size_t off = 0;
  auto alloc = [&](size_t bytes) -> char* {
    char* p = ws + off; off += (bytes + 255) & ~(size_t)255; return p;
  };
  u16* kvhB   = (u16*)alloc((size_t)N * 384 * 2);   // [k | v | h] bf16; aliased by hid after edge
  u16* xrB    = (u16*)alloc((size_t)N * 128 * 2);
  u16* qB     = (u16*)alloc((size_t)N * 128 * 2);
  u16* xnB    = (u16*)alloc((size_t)N * 128 * 2);
  int* csr    = (int*)alloc((size_t)E * 4);
  int* deg    = (int*)alloc((size_t)N * 4);
  int* rowptr = (int*)alloc((size_t)(N + 1) * 4);
  int* fill   = (int*)alloc((size_t)N * 4);
  float* dinv = (float*)alloc((size_t)N * 4);
  int NB = (N + 1023) >> 10;
  int* bsum   = (int*)alloc((size_t)NB * 4);
  int* boff   = (int*)alloc((size_t)NB * 4);
  u16* WcatT  = (u16*)alloc((size_t)640 * 128 * 2);
  float* bcat = (float*)alloc((size_t)640 * 4);
  u16* w1T    = (u16*)alloc((size_t)256 * 128 * 2);
  u16* w2T    = (u16*)alloc((size_t)128 * 256 * 2);
  u16* hid    = kvhB;            // alias: kvhB dead after k_edge (N*256*2 <= N*384*2)

  if (off > ws_size) return;     // bail cleanly if workspace too small

  hipMemsetAsync(deg, 0, (size_t)N * 4, stream);
  hipMemsetAsync(fill, 0, (size_t)N * 4, stream);

  k_prep_all<<<576, 256, 0, stream>>>(w_q, b_q, w_skip, b_skip, w_k, b_k, w_v, b_v, w_gcn,
                                      w1, w2, WcatT, bcat, w1T, w2T);
  k_hist<<<(E + 255) / 256, 256, 0, stream>>>(ei, E, deg);
  k_scan_a<<<NB, 256, 0, stream>>>(deg, N, bsum);
  k_scan_b<<<1, 1024, 0, stream>>>(bsum, NB, boff);
  k_scan_c<<<NB, 256, 0, stream>>>(deg, N, E, boff, rowptr, dinv);
  k_csr<<<(E + 255) / 256, 256, 0, stream>>>(ei, E, rowptr, fill, csr);

  int MB = (N + 127) / 128;
  k_gemm1<<<MB, 256, 0, stream>>>(x, WcatT, bcat, qB, xrB, kvhB, N);
  k_edge<<<(N + 3) / 4, 256, 0, stream>>>(qB, xrB, kvhB, csr, rowptr, dinv, b_gcn, w_beta,
                                          ln1_g, ln1_b, lw, gw, xnB, N);
  dim3 f1(MB, 2);
  k_ffn1<<<f1, 256, 0, stream>>>(xnB, w1T, b1, hid, N);
  k_ffn2<<<MB, 256, 0, stream>>>(hid, w2T, b2, xnB, ln2_g, ln2_b, outf, N);
}

// Round 10
// 443.159 us; speedup vs baseline: 1.1366x; 1.0275x over previous
//
#include <hip/hip_runtime.h>

typedef unsigned int u32;
typedef unsigned short u16;
typedef __attribute__((ext_vector_type(8))) short bf16x8;
typedef __attribute__((ext_vector_type(4))) float f32x4;

__device__ __forceinline__ float bf2f(u16 u){ return __uint_as_float(((u32)u) << 16); }
__device__ __forceinline__ float bf2f_lo(u32 u){ return __uint_as_float(u << 16); }
__device__ __forceinline__ float bf2f_hi(u32 u){ return __uint_as_float(u & 0xffff0000u); }
__device__ __forceinline__ u16 f2bf(float f){
  u32 x = __float_as_uint(f);
  return (u16)((x + 0x7fffu + ((x >> 16) & 1u)) >> 16);  // RNE
}

// ---------- prep: WcatT[640][128] ([q|skip|k|v|gcn], [outcol][k]) + bcat, w1T, w2T (bf16) ----------
__global__ void k_prep_all(const float* wq, const float* bq, const float* wsk, const float* bsk,
                           const float* wk, const float* bk, const float* wv, const float* bv,
                           const float* wg, const float* w1, const float* w2,
                           u16* WcatT, float* bcat, u16* w1T, u16* w2T){
  int idx = blockIdx.x * 256 + threadIdx.x;
  if (idx < 640 * 128){
    int col = idx >> 7, k = idx & 127;
    int blk = col >> 7, c = col & 127;
    const float* w = (blk==0)?wq:(blk==1)?wsk:(blk==2)?wk:(blk==3)?wv:wg;
    WcatT[idx] = f2bf(w[k * 128 + c]);
    if (k == 0){
      const float* b = (blk==0)?bq:(blk==1)?bsk:(blk==2)?bk:(blk==3)?bv:nullptr;
      bcat[col] = b ? b[c] : 0.0f;   // gcn bias added after aggregation
    }
  } else if (idx < 640*128 + 256*128){
    int j = idx - 640*128; int c = j >> 7, k = j & 127;
    w1T[j] = f2bf(w1[k * 256 + c]);
  } else if (idx < 640*128 + 256*128 + 128*256){
    int j = idx - (640*128 + 256*128); int c = j >> 8, k = j & 255;
    w2T[j] = f2bf(w2[k * 128 + c]);
  }
}

// ---------- graph prep (edge_index int32: src=ei[e], dst=ei[E+e]) ----------
__global__ void k_hist(const int* __restrict__ ei, int E, int* __restrict__ deg){
  int e = blockIdx.x * 256 + threadIdx.x;
  if (e >= E) return;
  atomicAdd(&deg[ei[E + e]], 1);
}
__global__ void k_scan_a(const int* __restrict__ deg, int N, int* __restrict__ bsum){
  __shared__ int sh[256];
  int b = blockIdx.x, t = threadIdx.x;
  int base = b * 1024 + t * 4, s = 0;
  #pragma unroll
  for (int j = 0; j < 4; j++){ int i = base + j; if (i < N) s += deg[i]; }
  sh[t] = s; __syncthreads();
  for (int off = 128; off > 0; off >>= 1){ if (t < off) sh[t] += sh[t + off]; __syncthreads(); }
  if (t == 0) bsum[b] = sh[0];
}
__global__ void k_scan_b(const int* __restrict__ bsum, int NB, int* __restrict__ boff){
  __shared__ int sh[1024];
  int t = threadIdx.x;
  int self = (t < NB) ? bsum[t] : 0;
  sh[t] = self; __syncthreads();
  for (int off = 1; off < 1024; off <<= 1){
    int v = sh[t]; int add = (t >= off) ? sh[t - off] : 0;
    __syncthreads(); sh[t] = v + add; __syncthreads();
  }
  if (t < NB) boff[t] = sh[t] - self;
}
// scan_c also emits dinv (deg already in registers)
__global__ void k_scan_c(const int* __restrict__ deg, int N, int E,
                         const int* __restrict__ boff, int* __restrict__ rowptr,
                         float* __restrict__ dinv){
  __shared__ int sh[256];
  int b = blockIdx.x, t = threadIdx.x;
  int base = b * 1024 + t * 4;
  int d[4]; int ts = 0;
  #pragma unroll
  for (int j = 0; j < 4; j++){ int i = base + j; d[j] = (i < N) ? deg[i] : 0; ts += d[j]; }
  sh[t] = ts; __syncthreads();
  for (int off = 1; off < 256; off <<= 1){
    int v = sh[t]; int add = (t >= off) ? sh[t - off] : 0;
    __syncthreads(); sh[t] = v + add; __syncthreads();
  }
  int excl = sh[t] - ts + boff[b];
  #pragma unroll
  for (int j = 0; j < 4; j++){
    int i = base + j;
    if (i < N){
      rowptr[i] = excl;
      dinv[i] = d[j] > 0 ? rsqrtf((float)d[j]) : 0.0f;
    }
    excl += d[j];
  }
  if (b == 0 && t == 0) rowptr[N] = E;
}
// csr fill: reuse deg as the per-node countdown (deg dead after scan_c)
__global__ void k_csr(const int* __restrict__ ei, int E,
                      const int* __restrict__ rowptr, int* __restrict__ deg, int* __restrict__ csr){
  int e = blockIdx.x * 256 + threadIdx.x;
  if (e >= E) return;
  int d = ei[E + e];
  int pos = rowptr[d] + atomicSub(&deg[d], 1) - 1;
  csr[pos] = ei[e];
}

// ---------- MFMA tile helpers: 128 rows x 128 halves, XOR-swizzled LDS ----------
__device__ __forceinline__ void stageTile(const u16* __restrict__ g, int ldg, int row0, int rclamp,
                                          int kofs, u16* lds){
  int t = threadIdx.x;
  #pragma unroll
  for (int p = 0; p < 8; p++){
    int chunk = p * 256 + t;
    int r = chunk >> 4;
    int cs = (chunk & 15) << 3;
    int rg = row0 + r; if (rg >= rclamp) rg = rclamp - 1;
    bf16x8 v = *(const bf16x8*)(g + (size_t)rg * ldg + kofs + cs);
    *(bf16x8*)(lds + r * 128 + (cs ^ ((r & 7) << 3))) = v;
  }
}
// stage from f32 source with inline bf16 conversion
__device__ __forceinline__ void stageTileF32(const float* __restrict__ g, int ldg, int row0,
                                             int rclamp, u16* lds){
  int t = threadIdx.x;
  #pragma unroll
  for (int p = 0; p < 8; p++){
    int chunk = p * 256 + t;
    int r = chunk >> 4;
    int cs = (chunk & 15) << 3;
    int rg = row0 + r; if (rg >= rclamp) rg = rclamp - 1;
    const float* src = g + (size_t)rg * ldg + cs;
    float4 a = *(const float4*)(src);
    float4 b = *(const float4*)(src + 4);
    u16* dst = lds + r * 128 + (cs ^ ((r & 7) << 3));
    ushort4 lo; lo.x = f2bf(a.x); lo.y = f2bf(a.y); lo.z = f2bf(a.z); lo.w = f2bf(a.w);
    ushort4 hi; hi.x = f2bf(b.x); hi.y = f2bf(b.y); hi.z = f2bf(b.z); hi.w = f2bf(b.w);
    *(ushort4*)dst = lo;
    *(ushort4*)(dst + 4) = hi;
  }
}
__device__ __forceinline__ bf16x8 ldFrag(const u16* lds, int r, int k0){
  return *(const bf16x8*)(lds + r * 128 + (k0 ^ ((r & 7) << 3)));
}

// ---------- GEMM1 (MFMA, col-loop): q,xr bf16; kvh block = [k | v | h*dinv] bf16 ----------
__global__ __launch_bounds__(256) void k_gemm1(const float* __restrict__ x, const u16* __restrict__ WcatT,
    const float* __restrict__ bcat, const float* __restrict__ dinv,
    u16* __restrict__ qB, u16* __restrict__ xrB, u16* __restrict__ kvhB, int N){
  __shared__ u16 As[128 * 128];
  __shared__ u16 Bs[128 * 128];
  int row0 = blockIdx.x * 128;
  stageTileF32(x, 128, row0, N, As);     // A staged ONCE for all 5 col-blocks
  int t = threadIdx.x, l = t & 63, w = t >> 6;
  int wm = w >> 1, wn = w & 1;
  int c16 = l & 15, g = l >> 4;
  for (int cb = 0; cb < 5; cb++){
    stageTile(WcatT, 128, cb * 128, 1 << 30, 0, Bs);
    __syncthreads();
    f32x4 acc[4][4];
    #pragma unroll
    for (int mi = 0; mi < 4; mi++)
      #pragma unroll
      for (int ni = 0; ni < 4; ni++) acc[mi][ni] = (f32x4){0.f, 0.f, 0.f, 0.f};
    #pragma unroll
    for (int kk = 0; kk < 4; kk++){
      int k0 = kk * 32 + g * 8;
      bf16x8 af[4], bfr[4];
      #pragma unroll
      for (int mi = 0; mi < 4; mi++) af[mi] = ldFrag(As, wm * 64 + mi * 16 + c16, k0);
      #pragma unroll
      for (int ni = 0; ni < 4; ni++) bfr[ni] = ldFrag(Bs, wn * 64 + ni * 16 + c16, k0);
      #pragma unroll
      for (int mi = 0; mi < 4; mi++)
        #pragma unroll
        for (int ni = 0; ni < 4; ni++)
          acc[mi][ni] = __builtin_amdgcn_mfma_f32_16x16x32_bf16(af[mi], bfr[ni], acc[mi][ni], 0, 0, 0);
    }
    float bias[4];
    #pragma unroll
    for (int ni = 0; ni < 4; ni++) bias[ni] = bcat[cb * 128 + wn * 64 + ni * 16 + c16];
    #pragma unroll
    for (int mi = 0; mi < 4; mi++){
      #pragma unroll
      for (int r = 0; r < 4; r++){
        int row = row0 + wm * 64 + mi * 16 + g * 4 + r;
        if (row < N){
          if (cb == 0 || cb == 1){
            u16* dst = (cb == 0 ? qB : xrB) + (size_t)row * 128;
            #pragma unroll
            for (int ni = 0; ni < 4; ni++)
              dst[wn * 64 + ni * 16 + c16] = f2bf(acc[mi][ni][r] + bias[ni]);
          } else if (cb == 4){           // h*dinv at u16 offset 256 (gcn bias applied later)
            float dv = dinv[row];
            u16* dst = kvhB + (size_t)row * 384 + 256;
            #pragma unroll
            for (int ni = 0; ni < 4; ni++)
              dst[wn * 64 + ni * 16 + c16] = f2bf(acc[mi][ni][r] * dv);
          } else {                       // k at offset 0, v at offset 128
            u16* dst = kvhB + (size_t)row * 384 + (cb - 2) * 128;
            #pragma unroll
            for (int ni = 0; ni < 4; ni++)
              dst[wn * 64 + ni * 16 + c16] = f2bf(acc[mi][ni][r] + bias[ni]);
          }
        }
      }
    }
    __syncthreads();   // Bs consumed; safe to restage next col-block
  }
}

// ---------- edge pass: half-wave per edge, 4 dims/lane; h pre-scaled (no dinv gather) ----------
__global__ __launch_bounds__(256) void k_edge(const u16* __restrict__ qB, const u16* __restrict__ xrB,
    const u16* __restrict__ kvhB,
    const int* __restrict__ csr, const int* __restrict__ rowptr, const float* __restrict__ dinv,
    const float* __restrict__ bgcn, const float* __restrict__ wbeta,
    const float* __restrict__ lng, const float* __restrict__ lnb,
    const float* __restrict__ lwp, const float* __restrict__ gwp,
    u16* __restrict__ xnB, int N){
  int lane = threadIdx.x & 63;
  int half = lane >> 5;
  int li = lane & 31;
  int d0 = li * 4;                      // dims d0..d0+3; head = li>>3 (8 lanes/head)
  int n = blockIdx.x * 4 + (threadIdx.x >> 6);
  if (n >= N) return;
  int ro = rowptr[n], re = rowptr[n + 1];
  uint2 qu = *(const uint2*)(qB + (size_t)n * 128 + d0);
  float q0 = bf2f_lo(qu.x), q1 = bf2f_hi(qu.x), q2 = bf2f_lo(qu.y), q3 = bf2f_hi(qu.y);
  float av0 = 0, av1 = 0, av2 = 0, av3 = 0;
  float ah0 = 0, ah1 = 0, ah2 = 0, ah3 = 0;
  float den = 0;
  const float SC = 0.17677669529663687f;  // 1/sqrt(32)
  for (int e = ro + half; e < re; e += 2){
    int s = csr[e];
    const u16* fb = kvhB + (size_t)s * 384;
    uint2 ku = *(const uint2*)(fb + d0);
    uint2 vu = *(const uint2*)(fb + 128 + d0);
    uint2 hu = *(const uint2*)(fb + 256 + d0);
    float part = q0 * bf2f_lo(ku.x) + q1 * bf2f_hi(ku.x)
               + q2 * bf2f_lo(ku.y) + q3 * bf2f_hi(ku.y);
    part += __shfl_xor(part, 1);        // 8-lane head group
    part += __shfl_xor(part, 2);
    part += __shfl_xor(part, 4);
    float p = __expf(part * SC);
    av0 += p * bf2f_lo(vu.x); av1 += p * bf2f_hi(vu.x);
    av2 += p * bf2f_lo(vu.y); av3 += p * bf2f_hi(vu.y);
    ah0 += bf2f_lo(hu.x); ah1 += bf2f_hi(hu.x);   // h pre-scaled by dinv[src]
    ah2 += bf2f_lo(hu.y); ah3 += bf2f_hi(hu.y);
    den += p;
  }
  // merge halves
  den += __shfl_xor(den, 32);
  av0 += __shfl_xor(av0, 32); av1 += __shfl_xor(av1, 32);
  av2 += __shfl_xor(av2, 32); av3 += __shfl_xor(av3, 32);
  ah0 += __shfl_xor(ah0, 32); ah1 += __shfl_xor(ah1, 32);
  ah2 += __shfl_xor(ah2, 32); ah3 += __shfl_xor(ah3, 32);
  float inv_den = den > 0 ? 1.0f / den : 0.0f;
  float at0 = av0 * inv_den, at1 = av1 * inv_den, at2 = av2 * inv_den, at3 = av3 * inv_den;
  uint2 xru = *(const uint2*)(xrB + (size_t)n * 128 + d0);
  float xr0 = bf2f_lo(xru.x), xr1 = bf2f_hi(xru.x), xr2 = bf2f_lo(xru.y), xr3 = bf2f_hi(xru.y);
  float4 wb0 = *(const float4*)(wbeta + d0);
  float4 wb1 = *(const float4*)(wbeta + 128 + d0);
  float4 wb2 = *(const float4*)(wbeta + 256 + d0);
  float z = at0 * wb0.x + at1 * wb0.y + at2 * wb0.z + at3 * wb0.w
          + xr0 * wb1.x + xr1 * wb1.y + xr2 * wb1.z + xr3 * wb1.w
          + (at0 - xr0) * wb2.x + (at1 - xr1) * wb2.y
          + (at2 - xr2) * wb2.z + (at3 - xr3) * wb2.w;
  z += __shfl_xor(z, 1); z += __shfl_xor(z, 2); z += __shfl_xor(z, 4);
  z += __shfl_xor(z, 8); z += __shfl_xor(z, 16);
  float beta = 1.0f / (1.0f + __expf(-z));
  float dn = dinv[n];
  float4 bg = *(const float4*)(bgcn + d0);
  float l0 = dn * ah0 + bg.x, l1 = dn * ah1 + bg.y, l2 = dn * ah2 + bg.z, l3 = dn * ah3 + bg.w;
  float lw = lwp[0], gw = gwp[0];
  float ib = 1.0f - beta;
  float t0 = 2.0f * (lw * l0 + gw * (beta * xr0 + ib * at0));
  float t1 = 2.0f * (lw * l1 + gw * (beta * xr1 + ib * at1));
  float t2 = 2.0f * (lw * l2 + gw * (beta * xr2 + ib * at2));
  float t3 = 2.0f * (lw * l3 + gw * (beta * xr3 + ib * at3));
  float s = t0 + t1 + t2 + t3;
  float sq = t0*t0 + t1*t1 + t2*t2 + t3*t3;
  s += __shfl_xor(s, 1);  sq += __shfl_xor(sq, 1);
  s += __shfl_xor(s, 2);  sq += __shfl_xor(sq, 2);
  s += __shfl_xor(s, 4);  sq += __shfl_xor(sq, 4);
  s += __shfl_xor(s, 8);  sq += __shfl_xor(sq, 8);
  s += __shfl_xor(s, 16); sq += __shfl_xor(sq, 16);
  float mu = s * (1.0f / 128.0f);
  float var = sq * (1.0f / 128.0f) - mu * mu;
  float inv = rsqrtf(var + 1e-5f);
  if (half == 0){
    float4 gm = *(const float4*)(lng + d0);
    float4 bt = *(const float4*)(lnb + d0);
    float o0 = (t0 - mu) * inv * gm.x + bt.x;
    float o1 = (t1 - mu) * inv * gm.y + bt.y;
    float o2 = (t2 - mu) * inv * gm.z + bt.z;
    float o3 = (t3 - mu) * inv * gm.w + bt.w;
    uint2 pk;
    pk.x = (u32)f2bf(o0) | ((u32)f2bf(o1) << 16);
    pk.y = (u32)f2bf(o2) | ((u32)f2bf(o3) << 16);
    *(uint2*)(xnB + (size_t)n * 128 + d0) = pk;
  }
}

// ---------- fused FFN: relu(xn@w1+b1)@w2 + b2 + xn, LN2 -> out. 64 rows/block, hid in LDS ----------
__global__ __launch_bounds__(256) void k_ffn(const u16* __restrict__ xnB, const u16* __restrict__ w1T,
    const float* __restrict__ b1, const u16* __restrict__ w2T, const float* __restrict__ b2,
    const float* __restrict__ g2, const float* __restrict__ bt2,
    float* __restrict__ out, int N){
  __shared__ u16 L[32768];  // 64KB. ph1: [xn 0..8192 | w1 8192..24576]; ph2: [hid 0..16384 | w2 16384..32768]
  int row0 = blockIdx.x * 64;
  int t = threadIdx.x, l = t & 63, w = t >> 6;   // 4 waves, wave w owns rows w*16..w*16+15
  int c16 = l & 15, g = l >> 4;
  // stage xn tile (64 x 128) -> L[0..8192)
  #pragma unroll
  for (int p = 0; p < 4; p++){
    int chunk = p * 256 + t;
    int r = chunk >> 4, cs = (chunk & 15) << 3;
    int rg = row0 + r; if (rg >= N) rg = N - 1;
    bf16x8 v = *(const bf16x8*)(xnB + (size_t)rg * 128 + cs);
    *(bf16x8*)(L + r * 128 + (cs ^ ((r & 7) << 3))) = v;
  }
  f32x4 acc1[2][8];
  #pragma unroll
  for (int cb = 0; cb < 2; cb++)
    #pragma unroll
    for (int ni = 0; ni < 8; ni++) acc1[cb][ni] = (f32x4){0.f, 0.f, 0.f, 0.f};
  for (int cb = 0; cb < 2; cb++){
    // stage w1T col-block (128 cols x 128 k) -> L[8192..24576)
    #pragma unroll
    for (int p = 0; p < 8; p++){
      int chunk = p * 256 + t;
      int r = chunk >> 4, cs = (chunk & 15) << 3;
      bf16x8 v = *(const bf16x8*)(w1T + (size_t)(cb * 128 + r) * 128 + cs);
      *(bf16x8*)(L + 8192 + r * 128 + (cs ^ ((r & 7) << 3))) = v;
    }
    __syncthreads();
    #pragma unroll
    for (int kk = 0; kk < 4; kk++){
      int k0 = kk * 32 + g * 8;
      bf16x8 af = ldFrag(L, w * 16 + c16, k0);
      #pragma unroll
      for (int ni = 0; ni < 8; ni++){
        bf16x8 bfr = ldFrag(L + 8192, ni * 16 + c16, k0);
        acc1[cb][ni] = __builtin_amdgcn_mfma_f32_16x16x32_bf16(af, bfr, acc1[cb][ni], 0, 0, 0);
      }
    }
    __syncthreads();  // w1 region free for restage / hid overwrite
  }
  // write hid tile (relu, bf16) -> L[0..16384), row stride 256, swizzled
  #pragma unroll
  for (int cb = 0; cb < 2; cb++){
    #pragma unroll
    for (int ni = 0; ni < 8; ni++){
      float bias = b1[cb * 128 + ni * 16 + c16];
      #pragma unroll
      for (int r = 0; r < 4; r++){
        int rl = w * 16 + g * 4 + r;
        int col = cb * 128 + ni * 16 + c16;
        L[rl * 256 + (col ^ ((rl & 7) << 3))] = f2bf(fmaxf(acc1[cb][ni][r] + bias, 0.f));
      }
    }
  }
  __syncthreads();
  f32x4 acc2[8];
  #pragma unroll
  for (int ni = 0; ni < 8; ni++) acc2[ni] = (f32x4){0.f, 0.f, 0.f, 0.f};
  for (int kc = 0; kc < 2; kc++){
    // stage w2T k-half (128 outcols x 128 k) -> L[16384..32768)
    #pragma unroll
    for (int p = 0; p < 8; p++){
      int chunk = p * 256 + t;
      int r = chunk >> 4, cs = (chunk & 15) << 3;
      bf16x8 v = *(const bf16x8*)(w2T + (size_t)r * 256 + kc * 128 + cs);
      *(bf16x8*)(L + 16384 + r * 128 + (cs ^ ((r & 7) << 3))) = v;
    }
    __syncthreads();
    #pragma unroll
    for (int kk = 0; kk < 4; kk++){
      int k0 = kk * 32 + g * 8;
      int rowl = w * 16 + c16;
      bf16x8 af = *(const bf16x8*)(L + rowl * 256 + ((kc * 128 + k0) ^ ((rowl & 7) << 3)));
      #pragma unroll
      for (int ni = 0; ni < 8; ni++){
        bf16x8 bfr = ldFrag(L + 16384, ni * 16 + c16, k0);
        acc2[ni] = __builtin_amdgcn_mfma_f32_16x16x32_bf16(af, bfr, acc2[ni], 0, 0, 0);
      }
    }
    __syncthreads();
  }
  float b2c[8], g2c[8], btc[8];
  #pragma unroll
  for (int ni = 0; ni < 8; ni++){
    int col = ni * 16 + c16;
    b2c[ni] = b2[col]; g2c[ni] = g2[col]; btc[ni] = bt2[col];
  }
  #pragma unroll
  for (int r = 0; r < 4; r++){
    int row = row0 + w * 16 + g * 4 + r;
    int rc = row < N ? row : N - 1;
    float z[8]; float s = 0.f, sq = 0.f;
    #pragma unroll
    for (int ni = 0; ni < 8; ni++){
      float xv = bf2f(xnB[(size_t)rc * 128 + ni * 16 + c16]);
      z[ni] = acc2[ni][r] + b2c[ni] + xv;
      s += z[ni]; sq += z[ni] * z[ni];
    }
    s += __shfl_xor(s, 1); sq += __shfl_xor(sq, 1);
    s += __shfl_xor(s, 2); sq += __shfl_xor(sq, 2);
    s += __shfl_xor(s, 4); sq += __shfl_xor(sq, 4);
    s += __shfl_xor(s, 8); sq += __shfl_xor(sq, 8);
    float mu = s * (1.0f / 128.0f);
    float var = sq * (1.0f / 128.0f) - mu * mu;
    float inv = rsqrtf(var + 1e-5f);
    if (row < N){
      #pragma unroll
      for (int ni = 0; ni < 8; ni++)
        out[(size_t)row * 128 + ni * 16 + c16] = (z[ni] - mu) * inv * g2c[ni] + btc[ni];
    }
  }
}

extern "C" void kernel_launch(void* const* d_in, const int* in_sizes, int n_in,
                              void* d_out, int out_size, void* d_ws, size_t ws_size,
                              hipStream_t stream){
  const float* x      = (const float*)d_in[0];
  const int*   ei     = (const int*)d_in[1];
  const float* w_gcn  = (const float*)d_in[2];
  const float* b_gcn  = (const float*)d_in[3];
  const float* w_q    = (const float*)d_in[4];
  const float* b_q    = (const float*)d_in[5];
  const float* w_k    = (const float*)d_in[6];
  const float* b_k    = (const float*)d_in[7];
  const float* w_v    = (const float*)d_in[8];
  const float* b_v    = (const float*)d_in[9];
  const float* w_skip = (const float*)d_in[10];
  const float* b_skip = (const float*)d_in[11];
  const float* w_beta = (const float*)d_in[12];
  const float* ln1_g  = (const float*)d_in[13];
  const float* ln1_b  = (const float*)d_in[14];
  const float* ln2_g  = (const float*)d_in[15];
  const float* ln2_b  = (const float*)d_in[16];
  const float* w1     = (const float*)d_in[17];
  const float* b1     = (const float*)d_in[18];
  const float* w2     = (const float*)d_in[19];
  const float* b2     = (const float*)d_in[20];
  const float* lw     = (const float*)d_in[21];
  const float* gw     = (const float*)d_in[22];
  int N = in_sizes[0] / 128;
  int E = in_sizes[1] / 2;
  float* outf = (float*)d_out;

  char* ws = (char*)d_ws;
  size_t off = 0;
  auto alloc = [&](size_t bytes) -> char* {
    char* p = ws + off; off += (bytes + 255) & ~(size_t)255; return p;
  };
  u16* kvhB   = (u16*)alloc((size_t)N * 384 * 2);   // [k | v | h*dinv] bf16, 768B/node
  u16* xrB    = (u16*)alloc((size_t)N * 128 * 2);
  u16* qB     = (u16*)alloc((size_t)N * 128 * 2);
  u16* xnB    = (u16*)alloc((size_t)N * 128 * 2);
  int* csr    = (int*)alloc((size_t)E * 4);
  int* deg    = (int*)alloc((size_t)N * 4);
  int* rowptr = (int*)alloc((size_t)(N + 1) * 4);
  float* dinv = (float*)alloc((size_t)N * 4);
  int NB = (N + 1023) >> 10;
  int* bsum   = (int*)alloc((size_t)NB * 4);
  int* boff   = (int*)alloc((size_t)NB * 4);
  u16* WcatT  = (u16*)alloc((size_t)640 * 128 * 2);
  float* bcat = (float*)alloc((size_t)640 * 4);
  u16* w1T    = (u16*)alloc((size_t)256 * 128 * 2);
  u16* w2T    = (u16*)alloc((size_t)128 * 256 * 2);

  if (off > ws_size) return;     // bail cleanly if workspace too small

  hipMemsetAsync(deg, 0, (size_t)N * 4, stream);

  k_prep_all<<<576, 256, 0, stream>>>(w_q, b_q, w_skip, b_skip, w_k, b_k, w_v, b_v, w_gcn,
                                      w1, w2, WcatT, bcat, w1T, w2T);
  k_hist<<<(E + 255) / 256, 256, 0, stream>>>(ei, E, deg);
  k_scan_a<<<NB, 256, 0, stream>>>(deg, N, bsum);
  k_scan_b<<<1, 1024, 0, stream>>>(bsum, NB, boff);
  k_scan_c<<<NB, 256, 0, stream>>>(deg, N, E, boff, rowptr, dinv);
  k_csr<<<(E + 255) / 256, 256, 0, stream>>>(ei, E, rowptr, deg, csr);

  int MB = (N + 127) / 128;
  k_gemm1<<<MB, 256, 0, stream>>>(x, WcatT, bcat, dinv, qB, xrB, kvhB, N);
  k_edge<<<(N + 3) / 4, 256, 0, stream>>>(qB, xrB, kvhB, csr, rowptr, dinv, b_gcn, w_beta,
                                          ln1_g, ln1_b, lw, gw, xnB, N);
  int MB64 = (N + 63) / 64;
  k_ffn<<<MB64, 256, 0, stream>>>(xnB, w1T, b1, w2T, b2, ln2_g, ln2_b, outf, N);
}

// Round 11
// 411.504 us; speedup vs baseline: 1.2241x; 1.0769x over previous
//
#include <hip/hip_runtime.h>

typedef unsigned int u32;
typedef unsigned short u16;
typedef __attribute__((ext_vector_type(8))) short bf16x8;
typedef __attribute__((ext_vector_type(4))) float f32x4;

__device__ __forceinline__ float bf2f(u16 u){ return __uint_as_float(((u32)u) << 16); }
__device__ __forceinline__ float bf2f_lo(u32 u){ return __uint_as_float(u << 16); }
__device__ __forceinline__ float bf2f_hi(u32 u){ return __uint_as_float(u & 0xffff0000u); }
__device__ __forceinline__ u16 f2bf(float f){
  u32 x = __float_as_uint(f);
  return (u16)((x + 0x7fffu + ((x >> 16) & 1u)) >> 16);  // RNE
}

// ---------- K1 merged: [hist | prep] ----------
// hist blocks [0, EB): in-degree histogram. prep blocks [EB, EB+576): weight transposes.
__global__ __launch_bounds__(256) void k_hist_prep(const int* __restrict__ ei, int E, int EB,
                           int* __restrict__ deg,
                           const float* wq, const float* bq, const float* wsk, const float* bsk,
                           const float* wk, const float* bk, const float* wv, const float* bv,
                           const float* wg, const float* w1, const float* w2,
                           u16* WcatT, float* bcat, u16* w1T, u16* w2T){
  int bid = blockIdx.x;
  if (bid < EB){
    int e = bid * 256 + threadIdx.x;
    if (e < E) atomicAdd(&deg[ei[E + e]], 1);
    return;
  }
  int idx = (bid - EB) * 256 + threadIdx.x;
  if (idx < 640 * 128){
    int col = idx >> 7, k = idx & 127;
    int blk = col >> 7, c = col & 127;
    const float* w = (blk==0)?wq:(blk==1)?wsk:(blk==2)?wk:(blk==3)?wv:wg;
    WcatT[idx] = f2bf(w[k * 128 + c]);
    if (k == 0){
      const float* b = (blk==0)?bq:(blk==1)?bsk:(blk==2)?bk:(blk==3)?bv:nullptr;
      bcat[col] = b ? b[c] : 0.0f;   // gcn bias added after aggregation
    }
  } else if (idx < 640*128 + 256*128){
    int j = idx - 640*128; int c = j >> 7, k = j & 127;
    w1T[j] = f2bf(w1[k * 256 + c]);
  } else if (idx < 640*128 + 256*128 + 128*256){
    int j = idx - (640*128 + 256*128); int c = j >> 8, k = j & 255;
    w2T[j] = f2bf(w2[k * 128 + c]);
  }
}

__global__ void k_scan_a(const int* __restrict__ deg, int N, int* __restrict__ bsum){
  __shared__ int sh[256];
  int b = blockIdx.x, t = threadIdx.x;
  int base = b * 1024 + t * 4, s = 0;
  #pragma unroll
  for (int j = 0; j < 4; j++){ int i = base + j; if (i < N) s += deg[i]; }
  sh[t] = s; __syncthreads();
  for (int off = 128; off > 0; off >>= 1){ if (t < off) sh[t] += sh[t + off]; __syncthreads(); }
  if (t == 0) bsum[b] = sh[0];
}
__global__ void k_scan_b(const int* __restrict__ bsum, int NB, int* __restrict__ boff){
  __shared__ int sh[1024];
  int t = threadIdx.x;
  int self = (t < NB) ? bsum[t] : 0;
  sh[t] = self; __syncthreads();
  for (int off = 1; off < 1024; off <<= 1){
    int v = sh[t]; int add = (t >= off) ? sh[t - off] : 0;
    __syncthreads(); sh[t] = v + add; __syncthreads();
  }
  if (t < NB) boff[t] = sh[t] - self;
}
// scan_c also emits dinv (deg already in registers)
__global__ void k_scan_c(const int* __restrict__ deg, int N, int E,
                         const int* __restrict__ boff, int* __restrict__ rowptr,
                         float* __restrict__ dinv){
  __shared__ int sh[256];
  int b = blockIdx.x, t = threadIdx.x;
  int base = b * 1024 + t * 4;
  int d[4]; int ts = 0;
  #pragma unroll
  for (int j = 0; j < 4; j++){ int i = base + j; d[j] = (i < N) ? deg[i] : 0; ts += d[j]; }
  sh[t] = ts; __syncthreads();
  for (int off = 1; off < 256; off <<= 1){
    int v = sh[t]; int add = (t >= off) ? sh[t - off] : 0;
    __syncthreads(); sh[t] = v + add; __syncthreads();
  }
  int excl = sh[t] - ts + boff[b];
  #pragma unroll
  for (int j = 0; j < 4; j++){
    int i = base + j;
    if (i < N){
      rowptr[i] = excl;
      dinv[i] = d[j] > 0 ? rsqrtf((float)d[j]) : 0.0f;
    }
    excl += d[j];
  }
  if (b == 0 && t == 0) rowptr[N] = E;
}

// ---------- MFMA tile helpers: 128 rows x 128 halves, XOR-swizzled LDS ----------
__device__ __forceinline__ void stageTile(const u16* __restrict__ g, int ldg, int row0, int rclamp,
                                          int kofs, u16* lds){
  int t = threadIdx.x;
  #pragma unroll
  for (int p = 0; p < 8; p++){
    int chunk = p * 256 + t;
    int r = chunk >> 4;
    int cs = (chunk & 15) << 3;
    int rg = row0 + r; if (rg >= rclamp) rg = rclamp - 1;
    bf16x8 v = *(const bf16x8*)(g + (size_t)rg * ldg + kofs + cs);
    *(bf16x8*)(lds + r * 128 + (cs ^ ((r & 7) << 3))) = v;
  }
}
// stage from f32 source with inline bf16 conversion
__device__ __forceinline__ void stageTileF32(const float* __restrict__ g, int ldg, int row0,
                                             int rclamp, u16* lds){
  int t = threadIdx.x;
  #pragma unroll
  for (int p = 0; p < 8; p++){
    int chunk = p * 256 + t;
    int r = chunk >> 4;
    int cs = (chunk & 15) << 3;
    int rg = row0 + r; if (rg >= rclamp) rg = rclamp - 1;
    const float* src = g + (size_t)rg * ldg + cs;
    float4 a = *(const float4*)(src);
    float4 b = *(const float4*)(src + 4);
    u16* dst = lds + r * 128 + (cs ^ ((r & 7) << 3));
    ushort4 lo; lo.x = f2bf(a.x); lo.y = f2bf(a.y); lo.z = f2bf(a.z); lo.w = f2bf(a.w);
    ushort4 hi; hi.x = f2bf(b.x); hi.y = f2bf(b.y); hi.z = f2bf(b.z); hi.w = f2bf(b.w);
    *(ushort4*)dst = lo;
    *(ushort4*)(dst + 4) = hi;
  }
}
__device__ __forceinline__ bf16x8 ldFrag(const u16* lds, int r, int k0){
  return *(const bf16x8*)(lds + r * 128 + (k0 ^ ((r & 7) << 3)));
}

// ---------- K5 merged: [gemm1 | csr] ----------
// gemm1 blocks [0, MB): col-loop MFMA GEMM. csr blocks [MB, MB+EB): CSR scatter fill.
__global__ __launch_bounds__(256) void k_gemm1_csr(const float* __restrict__ x,
    const u16* __restrict__ WcatT, const float* __restrict__ bcat, const float* __restrict__ dinv,
    u16* __restrict__ qB, u16* __restrict__ xrB, u16* __restrict__ kvhB, int N, int MB,
    const int* __restrict__ ei, int E, const int* __restrict__ rowptr,
    int* __restrict__ deg, int* __restrict__ csr){
  __shared__ u16 As[128 * 128];
  __shared__ u16 Bs[128 * 128];
  if (blockIdx.x >= MB){
    // csr fill: reuse deg as per-node countdown (deg dead after scan_c)
    int e = (blockIdx.x - MB) * 256 + threadIdx.x;
    if (e < E){
      int d = ei[E + e];
      int pos = rowptr[d] + atomicSub(&deg[d], 1) - 1;
      csr[pos] = ei[e];
    }
    return;
  }
  int row0 = blockIdx.x * 128;
  stageTileF32(x, 128, row0, N, As);     // A staged ONCE for all 5 col-blocks
  int t = threadIdx.x, l = t & 63, w = t >> 6;
  int wm = w >> 1, wn = w & 1;
  int c16 = l & 15, g = l >> 4;
  for (int cb = 0; cb < 5; cb++){
    stageTile(WcatT, 128, cb * 128, 1 << 30, 0, Bs);
    __syncthreads();
    f32x4 acc[4][4];
    #pragma unroll
    for (int mi = 0; mi < 4; mi++)
      #pragma unroll
      for (int ni = 0; ni < 4; ni++) acc[mi][ni] = (f32x4){0.f, 0.f, 0.f, 0.f};
    #pragma unroll
    for (int kk = 0; kk < 4; kk++){
      int k0 = kk * 32 + g * 8;
      bf16x8 af[4], bfr[4];
      #pragma unroll
      for (int mi = 0; mi < 4; mi++) af[mi] = ldFrag(As, wm * 64 + mi * 16 + c16, k0);
      #pragma unroll
      for (int ni = 0; ni < 4; ni++) bfr[ni] = ldFrag(Bs, wn * 64 + ni * 16 + c16, k0);
      #pragma unroll
      for (int mi = 0; mi < 4; mi++)
        #pragma unroll
        for (int ni = 0; ni < 4; ni++)
          acc[mi][ni] = __builtin_amdgcn_mfma_f32_16x16x32_bf16(af[mi], bfr[ni], acc[mi][ni], 0, 0, 0);
    }
    float bias[4];
    #pragma unroll
    for (int ni = 0; ni < 4; ni++) bias[ni] = bcat[cb * 128 + wn * 64 + ni * 16 + c16];
    #pragma unroll
    for (int mi = 0; mi < 4; mi++){
      #pragma unroll
      for (int r = 0; r < 4; r++){
        int row = row0 + wm * 64 + mi * 16 + g * 4 + r;
        if (row < N){
          if (cb == 0 || cb == 1){
            u16* dst = (cb == 0 ? qB : xrB) + (size_t)row * 128;
            #pragma unroll
            for (int ni = 0; ni < 4; ni++)
              dst[wn * 64 + ni * 16 + c16] = f2bf(acc[mi][ni][r] + bias[ni]);
          } else if (cb == 4){           // h*dinv at u16 offset 256 (gcn bias applied later)
            float dv = dinv[row];
            u16* dst = kvhB + (size_t)row * 384 + 256;
            #pragma unroll
            for (int ni = 0; ni < 4; ni++)
              dst[wn * 64 + ni * 16 + c16] = f2bf(acc[mi][ni][r] * dv);
          } else {                       // k at offset 0, v at offset 128
            u16* dst = kvhB + (size_t)row * 384 + (cb - 2) * 128;
            #pragma unroll
            for (int ni = 0; ni < 4; ni++)
              dst[wn * 64 + ni * 16 + c16] = f2bf(acc[mi][ni][r] + bias[ni]);
          }
        }
      }
    }
    __syncthreads();   // Bs consumed; safe to restage next col-block
  }
}

// ---------- edge pass: half-wave per edge, 4 dims/lane; h pre-scaled (no dinv gather) ----------
__global__ __launch_bounds__(256) void k_edge(const u16* __restrict__ qB, const u16* __restrict__ xrB,
    const u16* __restrict__ kvhB,
    const int* __restrict__ csr, const int* __restrict__ rowptr, const float* __restrict__ dinv,
    const float* __restrict__ bgcn, const float* __restrict__ wbeta,
    const float* __restrict__ lng, const float* __restrict__ lnb,
    const float* __restrict__ lwp, const float* __restrict__ gwp,
    u16* __restrict__ xnB, int N){
  int lane = threadIdx.x & 63;
  int half = lane >> 5;
  int li = lane & 31;
  int d0 = li * 4;                      // dims d0..d0+3; head = li>>3 (8 lanes/head)
  int n = blockIdx.x * 4 + (threadIdx.x >> 6);
  if (n >= N) return;
  int ro = rowptr[n], re = rowptr[n + 1];
  uint2 qu = *(const uint2*)(qB + (size_t)n * 128 + d0);
  float q0 = bf2f_lo(qu.x), q1 = bf2f_hi(qu.x), q2 = bf2f_lo(qu.y), q3 = bf2f_hi(qu.y);
  float av0 = 0, av1 = 0, av2 = 0, av3 = 0;
  float ah0 = 0, ah1 = 0, ah2 = 0, ah3 = 0;
  float den = 0;
  const float SC = 0.17677669529663687f;  // 1/sqrt(32)
  for (int e = ro + half; e < re; e += 2){
    int s = csr[e];
    const u16* fb = kvhB + (size_t)s * 384;
    uint2 ku = *(const uint2*)(fb + d0);
    uint2 vu = *(const uint2*)(fb + 128 + d0);
    uint2 hu = *(const uint2*)(fb + 256 + d0);
    float part = q0 * bf2f_lo(ku.x) + q1 * bf2f_hi(ku.x)
               + q2 * bf2f_lo(ku.y) + q3 * bf2f_hi(ku.y);
    part += __shfl_xor(part, 1);        // 8-lane head group
    part += __shfl_xor(part, 2);
    part += __shfl_xor(part, 4);
    float p = __expf(part * SC);
    av0 += p * bf2f_lo(vu.x); av1 += p * bf2f_hi(vu.x);
    av2 += p * bf2f_lo(vu.y); av3 += p * bf2f_hi(vu.y);
    ah0 += bf2f_lo(hu.x); ah1 += bf2f_hi(hu.x);   // h pre-scaled by dinv[src]
    ah2 += bf2f_lo(hu.y); ah3 += bf2f_hi(hu.y);
    den += p;
  }
  // merge halves
  den += __shfl_xor(den, 32);
  av0 += __shfl_xor(av0, 32); av1 += __shfl_xor(av1, 32);
  av2 += __shfl_xor(av2, 32); av3 += __shfl_xor(av3, 32);
  ah0 += __shfl_xor(ah0, 32); ah1 += __shfl_xor(ah1, 32);
  ah2 += __shfl_xor(ah2, 32); ah3 += __shfl_xor(ah3, 32);
  float inv_den = den > 0 ? 1.0f / den : 0.0f;
  float at0 = av0 * inv_den, at1 = av1 * inv_den, at2 = av2 * inv_den, at3 = av3 * inv_den;
  uint2 xru = *(const uint2*)(xrB + (size_t)n * 128 + d0);
  float xr0 = bf2f_lo(xru.x), xr1 = bf2f_hi(xru.x), xr2 = bf2f_lo(xru.y), xr3 = bf2f_hi(xru.y);
  float4 wb0 = *(const float4*)(wbeta + d0);
  float4 wb1 = *(const float4*)(wbeta + 128 + d0);
  float4 wb2 = *(const float4*)(wbeta + 256 + d0);
  float z = at0 * wb0.x + at1 * wb0.y + at2 * wb0.z + at3 * wb0.w
          + xr0 * wb1.x + xr1 * wb1.y + xr2 * wb1.z + xr3 * wb1.w
          + (at0 - xr0) * wb2.x + (at1 - xr1) * wb2.y
          + (at2 - xr2) * wb2.z + (at3 - xr3) * wb2.w;
  z += __shfl_xor(z, 1); z += __shfl_xor(z, 2); z += __shfl_xor(z, 4);
  z += __shfl_xor(z, 8); z += __shfl_xor(z, 16);
  float beta = 1.0f / (1.0f + __expf(-z));
  float dn = dinv[n];
  float4 bg = *(const float4*)(bgcn + d0);
  float l0 = dn * ah0 + bg.x, l1 = dn * ah1 + bg.y, l2 = dn * ah2 + bg.z, l3 = dn * ah3 + bg.w;
  float lw = lwp[0], gw = gwp[0];
  float ib = 1.0f - beta;
  float t0 = 2.0f * (lw * l0 + gw * (beta * xr0 + ib * at0));
  float t1 = 2.0f * (lw * l1 + gw * (beta * xr1 + ib * at1));
  float t2 = 2.0f * (lw * l2 + gw * (beta * xr2 + ib * at2));
  float t3 = 2.0f * (lw * l3 + gw * (beta * xr3 + ib * at3));
  float s = t0 + t1 + t2 + t3;
  float sq = t0*t0 + t1*t1 + t2*t2 + t3*t3;
  s += __shfl_xor(s, 1);  sq += __shfl_xor(sq, 1);
  s += __shfl_xor(s, 2);  sq += __shfl_xor(sq, 2);
  s += __shfl_xor(s, 4);  sq += __shfl_xor(sq, 4);
  s += __shfl_xor(s, 8);  sq += __shfl_xor(sq, 8);
  s += __shfl_xor(s, 16); sq += __shfl_xor(sq, 16);
  float mu = s * (1.0f / 128.0f);
  float var = sq * (1.0f / 128.0f) - mu * mu;
  float inv = rsqrtf(var + 1e-5f);
  if (half == 0){
    float4 gm = *(const float4*)(lng + d0);
    float4 bt = *(const float4*)(lnb + d0);
    float o0 = (t0 - mu) * inv * gm.x + bt.x;
    float o1 = (t1 - mu) * inv * gm.y + bt.y;
    float o2 = (t2 - mu) * inv * gm.z + bt.z;
    float o3 = (t3 - mu) * inv * gm.w + bt.w;
    uint2 pk;
    pk.x = (u32)f2bf(o0) | ((u32)f2bf(o1) << 16);
    pk.y = (u32)f2bf(o2) | ((u32)f2bf(o3) << 16);
    *(uint2*)(xnB + (size_t)n * 128 + d0) = pk;
  }
}

// ---------- fused FFN: relu(xn@w1+b1)@w2 + b2 + xn, LN2 -> out. 64 rows/block, hid in LDS ----------
__global__ __launch_bounds__(256) void k_ffn(const u16* __restrict__ xnB, const u16* __restrict__ w1T,
    const float* __restrict__ b1, const u16* __restrict__ w2T, const float* __restrict__ b2,
    const float* __restrict__ g2, const float* __restrict__ bt2,
    float* __restrict__ out, int N){
  __shared__ u16 L[32768];  // 64KB. ph1: [xn 0..8192 | w1 8192..24576]; ph2: [hid 0..16384 | w2 16384..32768]
  int row0 = blockIdx.x * 64;
  int t = threadIdx.x, l = t & 63, w = t >> 6;   // 4 waves, wave w owns rows w*16..w*16+15
  int c16 = l & 15, g = l >> 4;
  // stage xn tile (64 x 128) -> L[0..8192)
  #pragma unroll
  for (int p = 0; p < 4; p++){
    int chunk = p * 256 + t;
    int r = chunk >> 4, cs = (chunk & 15) << 3;
    int rg = row0 + r; if (rg >= N) rg = N - 1;
    bf16x8 v = *(const bf16x8*)(xnB + (size_t)rg * 128 + cs);
    *(bf16x8*)(L + r * 128 + (cs ^ ((r & 7) << 3))) = v;
  }
  f32x4 acc1[2][8];
  #pragma unroll
  for (int cb = 0; cb < 2; cb++)
    #pragma unroll
    for (int ni = 0; ni < 8; ni++) acc1[cb][ni] = (f32x4){0.f, 0.f, 0.f, 0.f};
  for (int cb = 0; cb < 2; cb++){
    // stage w1T col-block (128 cols x 128 k) -> L[8192..24576)
    #pragma unroll
    for (int p = 0; p < 8; p++){
      int chunk = p * 256 + t;
      int r = chunk >> 4, cs = (chunk & 15) << 3;
      bf16x8 v = *(const bf16x8*)(w1T + (size_t)(cb * 128 + r) * 128 + cs);
      *(bf16x8*)(L + 8192 + r * 128 + (cs ^ ((r & 7) << 3))) = v;
    }
    __syncthreads();
    #pragma unroll
    for (int kk = 0; kk < 4; kk++){
      int k0 = kk * 32 + g * 8;
      bf16x8 af = ldFrag(L, w * 16 + c16, k0);
      #pragma unroll
      for (int ni = 0; ni < 8; ni++){
        bf16x8 bfr = ldFrag(L + 8192, ni * 16 + c16, k0);
        acc1[cb][ni] = __builtin_amdgcn_mfma_f32_16x16x32_bf16(af, bfr, acc1[cb][ni], 0, 0, 0);
      }
    }
    __syncthreads();  // w1 region free for restage / hid overwrite
  }
  // write hid tile (relu, bf16) -> L[0..16384), row stride 256, swizzled
  #pragma unroll
  for (int cb = 0; cb < 2; cb++){
    #pragma unroll
    for (int ni = 0; ni < 8; ni++){
      float bias = b1[cb * 128 + ni * 16 + c16];
      #pragma unroll
      for (int r = 0; r < 4; r++){
        int rl = w * 16 + g * 4 + r;
        int col = cb * 128 + ni * 16 + c16;
        L[rl * 256 + (col ^ ((rl & 7) << 3))] = f2bf(fmaxf(acc1[cb][ni][r] + bias, 0.f));
      }
    }
  }
  __syncthreads();
  f32x4 acc2[8];
  #pragma unroll
  for (int ni = 0; ni < 8; ni++) acc2[ni] = (f32x4){0.f, 0.f, 0.f, 0.f};
  for (int kc = 0; kc < 2; kc++){
    // stage w2T k-half (128 outcols x 128 k) -> L[16384..32768)
    #pragma unroll
    for (int p = 0; p < 8; p++){
      int chunk = p * 256 + t;
      int r = chunk >> 4, cs = (chunk & 15) << 3;
      bf16x8 v = *(const bf16x8*)(w2T + (size_t)r * 256 + kc * 128 + cs);
      *(bf16x8*)(L + 16384 + r * 128 + (cs ^ ((r & 7) << 3))) = v;
    }
    __syncthreads();
    #pragma unroll
    for (int kk = 0; kk < 4; kk++){
      int k0 = kk * 32 + g * 8;
      int rowl = w * 16 + c16;
      bf16x8 af = *(const bf16x8*)(L + rowl * 256 + ((kc * 128 + k0) ^ ((rowl & 7) << 3)));
      #pragma unroll
      for (int ni = 0; ni < 8; ni++){
        bf16x8 bfr = ldFrag(L + 16384, ni * 16 + c16, k0);
        acc2[ni] = __builtin_amdgcn_mfma_f32_16x16x32_bf16(af, bfr, acc2[ni], 0, 0, 0);
      }
    }
    __syncthreads();
  }
  float b2c[8], g2c[8], btc[8];
  #pragma unroll
  for (int ni = 0; ni < 8; ni++){
    int col = ni * 16 + c16;
    b2c[ni] = b2[col]; g2c[ni] = g2[col]; btc[ni] = bt2[col];
  }
  #pragma unroll
  for (int r = 0; r < 4; r++){
    int row = row0 + w * 16 + g * 4 + r;
    int rc = row < N ? row : N - 1;
    float z[8]; float s = 0.f, sq = 0.f;
    #pragma unroll
    for (int ni = 0; ni < 8; ni++){
      float xv = bf2f(xnB[(size_t)rc * 128 + ni * 16 + c16]);
      z[ni] = acc2[ni][r] + b2c[ni] + xv;
      s += z[ni]; sq += z[ni] * z[ni];
    }
    s += __shfl_xor(s, 1); sq += __shfl_xor(sq, 1);
    s += __shfl_xor(s, 2); sq += __shfl_xor(sq, 2);
    s += __shfl_xor(s, 4); sq += __shfl_xor(sq, 4);
    s += __shfl_xor(s, 8); sq += __shfl_xor(sq, 8);
    float mu = s * (1.0f / 128.0f);
    float var = sq * (1.0f / 128.0f) - mu * mu;
    float inv = rsqrtf(var + 1e-5f);
    if (row < N){
      #pragma unroll
      for (int ni = 0; ni < 8; ni++)
        out[(size_t)row * 128 + ni * 16 + c16] = (z[ni] - mu) * inv * g2c[ni] + btc[ni];
    }
  }
}

extern "C" void kernel_launch(void* const* d_in, const int* in_sizes, int n_in,
                              void* d_out, int out_size, void* d_ws, size_t ws_size,
                              hipStream_t stream){
  const float* x      = (const float*)d_in[0];
  const int*   ei     = (const int*)d_in[1];
  const float* w_gcn  = (const float*)d_in[2];
  const float* b_gcn  = (const float*)d_in[3];
  const float* w_q    = (const float*)d_in[4];
  const float* b_q    = (const float*)d_in[5];
  const float* w_k    = (const float*)d_in[6];
  const float* b_k    = (const float*)d_in[7];
  const float* w_v    = (const float*)d_in[8];
  const float* b_v    = (const float*)d_in[9];
  const float* w_skip = (const float*)d_in[10];
  const float* b_skip = (const float*)d_in[11];
  const float* w_beta = (const float*)d_in[12];
  const float* ln1_g  = (const float*)d_in[13];
  const float* ln1_b  = (const float*)d_in[14];
  const float* ln2_g  = (const float*)d_in[15];
  const float* ln2_b  = (const float*)d_in[16];
  const float* w1     = (const float*)d_in[17];
  const float* b1     = (const float*)d_in[18];
  const float* w2     = (const float*)d_in[19];
  const float* b2     = (const float*)d_in[20];
  const float* lw     = (const float*)d_in[21];
  const float* gw     = (const float*)d_in[22];
  int N = in_sizes[0] / 128;
  int E = in_sizes[1] / 2;
  float* outf = (float*)d_out;

  char* ws = (char*)d_ws;
  size_t off = 0;
  auto alloc = [&](size_t bytes) -> char* {
    char* p = ws + off; off += (bytes + 255) & ~(size_t)255; return p;
  };
  u16* kvhB   = (u16*)alloc((size_t)N * 384 * 2);   // [k | v | h*dinv] bf16, 768B/node
  u16* xrB    = (u16*)alloc((size_t)N * 128 * 2);
  u16* qB     = (u16*)alloc((size_t)N * 128 * 2);
  u16* xnB    = (u16*)alloc((size_t)N * 128 * 2);
  int* csr    = (int*)alloc((size_t)E * 4);
  int* deg    = (int*)alloc((size_t)N * 4);
  int* rowptr = (int*)alloc((size_t)(N + 1) * 4);
  float* dinv = (float*)alloc((size_t)N * 4);
  int NB = (N + 1023) >> 10;
  int* bsum   = (int*)alloc((size_t)NB * 4);
  int* boff   = (int*)alloc((size_t)NB * 4);
  u16* WcatT  = (u16*)alloc((size_t)640 * 128 * 2);
  float* bcat = (float*)alloc((size_t)640 * 4);
  u16* w1T    = (u16*)alloc((size_t)256 * 128 * 2);
  u16* w2T    = (u16*)alloc((size_t)128 * 256 * 2);

  if (off > ws_size) return;     // bail cleanly if workspace too small

  hipMemsetAsync(deg, 0, (size_t)N * 4, stream);

  int EB = (E + 255) / 256;
  // K1: [hist | prep] — independent work co-scheduled in one dispatch
  k_hist_prep<<<EB + 576, 256, 0, stream>>>(ei, E, EB, deg,
                                            w_q, b_q, w_skip, b_skip, w_k, b_k, w_v, b_v, w_gcn,
                                            w1, w2, WcatT, bcat, w1T, w2T);
  k_scan_a<<<NB, 256, 0, stream>>>(deg, N, bsum);
  k_scan_b<<<1, 1024, 0, stream>>>(bsum, NB, boff);
  k_scan_c<<<NB, 256, 0, stream>>>(deg, N, E, boff, rowptr, dinv);

  int MB = (N + 127) / 128;
  // K5: [gemm1 | csr] — csr (atomic/latency-bound) hides under gemm1 (MFMA-bound)
  k_gemm1_csr<<<MB + EB, 256, 0, stream>>>(x, WcatT, bcat, dinv, qB, xrB, kvhB, N, MB,
                                           ei, E, rowptr, deg, csr);
  k_edge<<<(N + 3) / 4, 256, 0, stream>>>(qB, xrB, kvhB, csr, rowptr, dinv, b_gcn, w_beta,
                                          ln1_g, ln1_b, lw, gw, xnB, N);
  int MB64 = (N + 63) / 64;
  k_ffn<<<MB64, 256, 0, stream>>>(xnB, w1T, b1, w2T, b2, ln2_g, ln2_b, outf, N);
}